// Round 1
// baseline (478.741 us; speedup 1.0000x reference)
//
#include <hip/hip_runtime.h>
#include <math.h>

#define BB 2
#define NN 2048
#define HD 256
#define NH 8
#define DH 32
#define NTOK (BB*NN)   // 4096

// ---------------- LayerNorm: one wave per 256-wide row ----------------
__global__ __launch_bounds__(256) void ln_kernel(const float* __restrict__ x,
    const float* __restrict__ g, const float* __restrict__ bta,
    float* __restrict__ y)
{
  int row  = blockIdx.x * 4 + (threadIdx.x >> 6);
  int lane = threadIdx.x & 63;
  const float* xr = x + (size_t)row * HD + lane * 4;
  float4 v = *(const float4*)xr;
  float s = v.x + v.y + v.z + v.w;
  #pragma unroll
  for (int off = 32; off > 0; off >>= 1) s += __shfl_xor(s, off);
  float mu = s * (1.0f / HD);
  float dx0 = v.x - mu, dx1 = v.y - mu, dx2 = v.z - mu, dx3 = v.w - mu;
  float ss = dx0*dx0 + dx1*dx1 + dx2*dx2 + dx3*dx3;
  #pragma unroll
  for (int off = 32; off > 0; off >>= 1) ss += __shfl_xor(ss, off);
  float rinv = rsqrtf(ss * (1.0f / HD) + 1e-5f);
  float4 gv = *(const float4*)(g   + lane * 4);
  float4 bv = *(const float4*)(bta + lane * 4);
  float4 o;
  o.x = dx0 * rinv * gv.x + bv.x;
  o.y = dx1 * rinv * gv.y + bv.y;
  o.z = dx2 * rinv * gv.z + bv.z;
  o.w = dx3 * rinv * gv.w + bv.w;
  *(float4*)(y + (size_t)row * HD + lane * 4) = o;
}

// ---------------- fp32 tiled GEMM: C[M,N] = A[M,K] @ W[K,N] (+bias, ACT, RES) ----------------
// BM=BN=64, BK=16, 256 threads, 4x4 microtile.
template<int ACT, int RES>
__global__ __launch_bounds__(256) void gemm_kernel(const float* __restrict__ A,
    const float* __restrict__ W, const float* __restrict__ bias,
    const float* __restrict__ resid, float* __restrict__ C,
    int M, int N, int K)
{
  __shared__ float As[16][64];   // [k][m]
  __shared__ float Ws[16][64];   // [k][n]
  int t  = threadIdx.x;
  int tx = t & 15, ty = t >> 4;
  int m0 = blockIdx.y * 64, n0 = blockIdx.x * 64;
  float acc[4][4];
  #pragma unroll
  for (int i = 0; i < 4; i++)
    #pragma unroll
    for (int j = 0; j < 4; j++) acc[i][j] = 0.f;

  int arow = t >> 2, akp = (t & 3) * 4;     // A-tile: 1 float4 per thread
  int wkr  = t >> 4, wnp = (t & 15) * 4;    // W-tile: 1 float4 per thread

  for (int k0 = 0; k0 < K; k0 += 16) {
    __syncthreads();
    float4 av = *(const float4*)&A[(size_t)(m0 + arow) * K + k0 + akp];
    As[akp + 0][arow] = av.x; As[akp + 1][arow] = av.y;
    As[akp + 2][arow] = av.z; As[akp + 3][arow] = av.w;
    float4 wvv = *(const float4*)&W[(size_t)(k0 + wkr) * N + n0 + wnp];
    *(float4*)&Ws[wkr][wnp] = wvv;
    __syncthreads();
    #pragma unroll
    for (int kk = 0; kk < 16; kk++) {
      float4 a4 = *(const float4*)&As[kk][ty * 4];
      float4 b4 = *(const float4*)&Ws[kk][tx * 4];
      float aa[4] = {a4.x, a4.y, a4.z, a4.w};
      float bb[4] = {b4.x, b4.y, b4.z, b4.w};
      #pragma unroll
      for (int i = 0; i < 4; i++)
        #pragma unroll
        for (int j = 0; j < 4; j++) acc[i][j] += aa[i] * bb[j];
    }
  }

  #pragma unroll
  for (int i = 0; i < 4; i++) {
    int m = m0 + ty * 4 + i;
    float4 o;
    float* op = &o.x;
    #pragma unroll
    for (int j = 0; j < 4; j++) {
      int n = n0 + tx * 4 + j;
      float vv = acc[i][j] + bias[n];
      if (ACT == 1) vv = 0.5f * vv * (1.0f + erff(vv * 0.70710678118654752f));
      if (RES)      vv += resid[(size_t)m * N + n];
      op[j] = vv;
    }
    *(float4*)&C[(size_t)m * N + n0 + tx * 4] = o;
  }
}

// ---------------- Flash attention with adjacency-modified softmax ----------------
// Block: 256 threads = (b, head, 64-row Q tile). Thread t: row r = t>>2, col-group cg = t&3
// (owns k-columns c = 4j+cg, j=0..15). Online weighted softmax:
//   l = qk/sqrt(32) + (2a-1);  p = (0.25+0.75a)*exp(l - M);  out = sum(p*v)/sum(p)
__global__ __launch_bounds__(256) void attn_kernel(
    const float* __restrict__ q, const float* __restrict__ k,
    const float* __restrict__ v, const float* __restrict__ adj,
    float* __restrict__ out)
{
  __shared__ float Ks[64][36];   // stride 36 words: conflict-free float4 reads, 16B aligned
  __shared__ float Vs[64][36];
  __shared__ float Adj[64][68];  // stride 68 words

  int b = blockIdx.z, h = blockIdx.y, qt = blockIdx.x;
  int t = threadIdx.x;
  int r = t >> 2;
  int cg = t & 3;
  int qrow = qt * 64 + r;

  float4 q4[8];
  const float* qg = q + ((size_t)(b * NN + qrow) * HD) + h * DH;
  #pragma unroll
  for (int i = 0; i < 8; i++) q4[i] = *(const float4*)(qg + i * 4);

  float M = -3.0e38f, S = 0.f;
  float O[32];
  #pragma unroll
  for (int i = 0; i < 32; i++) O[i] = 0.f;
  const float inv_sqrt_d = 0.17677669529663687f;  // 1/sqrt(32)

  for (int kt0 = 0; kt0 < NN; kt0 += 64) {
    __syncthreads();
    {   // K/V tiles: 2x contiguous float4 each per thread
      int fl = t * 2;
      int row = fl >> 3, dp = (fl & 7) * 4;
      const float* kg = k + ((size_t)(b * NN + kt0 + row) * HD) + h * DH + dp;
      float4 k0v = *(const float4*)kg;
      float4 k1v = *(const float4*)(kg + 4);
      *(float4*)&Ks[row][dp] = k0v;  *(float4*)&Ks[row][dp + 4] = k1v;
      const float* vg = v + ((size_t)(b * NN + kt0 + row) * HD) + h * DH + dp;
      float4 v0v = *(const float4*)vg;
      float4 v1v = *(const float4*)(vg + 4);
      *(float4*)&Vs[row][dp] = v0v;  *(float4*)&Vs[row][dp + 4] = v1v;
    }
    {   // adjacency tile 64x64: 4 float4 per thread, coalesced
      #pragma unroll
      for (int i = 0; i < 4; i++) {
        int fl = t + 256 * i;
        int ar = fl >> 4, cp = (fl & 15) * 4;
        float4 a4 = *(const float4*)&adj[((size_t)(b * NN + qt * 64 + ar)) * NN + kt0 + cp];
        *(float4*)&Adj[ar][cp] = a4;
      }
    }
    __syncthreads();

    float lv[16];
    float tmax = -3.0e38f;
    #pragma unroll
    for (int j = 0; j < 16; j++) {
      int c = j * 4 + cg;
      float s = 0.f;
      #pragma unroll
      for (int dd = 0; dd < 8; dd++) {
        float4 k4 = *(const float4*)&Ks[c][dd * 4];
        s += q4[dd].x * k4.x + q4[dd].y * k4.y + q4[dd].z * k4.z + q4[dd].w * k4.w;
      }
      float a = Adj[r][c];
      float l = s * inv_sqrt_d + 2.0f * a - 1.0f;
      lv[j] = l;
      tmax = fmaxf(tmax, l);
    }
    tmax = fmaxf(tmax, __shfl_xor(tmax, 1));
    tmax = fmaxf(tmax, __shfl_xor(tmax, 2));
    float mnew = fmaxf(M, tmax);
    float scale = __expf(M - mnew);
    S *= scale;
    #pragma unroll
    for (int i = 0; i < 32; i++) O[i] *= scale;
    M = mnew;

    #pragma unroll
    for (int j = 0; j < 16; j++) {
      int c = j * 4 + cg;
      float a = Adj[r][c];
      float p = (0.25f + 0.75f * a) * __expf(lv[j] - M);
      S += p;
      #pragma unroll
      for (int dd = 0; dd < 8; dd++) {
        float4 v4 = *(const float4*)&Vs[c][dd * 4];
        O[dd*4+0] += p * v4.x; O[dd*4+1] += p * v4.y;
        O[dd*4+2] += p * v4.z; O[dd*4+3] += p * v4.w;
      }
    }
  }

  S += __shfl_xor(S, 1);  S += __shfl_xor(S, 2);
  #pragma unroll
  for (int i = 0; i < 32; i++) { O[i] += __shfl_xor(O[i], 1); O[i] += __shfl_xor(O[i], 2); }

  if (cg == 0) {
    float is = 1.0f / S;
    float* og = out + ((size_t)(b * NN + qrow) * HD) + h * DH;
    #pragma unroll
    for (int i = 0; i < 8; i++) {
      float4 o4 = make_float4(O[i*4] * is, O[i*4+1] * is, O[i*4+2] * is, O[i*4+3] * is);
      *(float4*)(og + i * 4) = o4;
    }
  }
}

extern "C" void kernel_launch(void* const* d_in, const int* in_sizes, int n_in,
                              void* d_out, int out_size, void* d_ws, size_t ws_size,
                              hipStream_t stream)
{
  const float* hidden    = (const float*)d_in[0];
  const float* adjacency = (const float*)d_in[1];
  // d_in[2] = positions (unused by the reference)
  const float* wq  = (const float*)d_in[3];
  const float* bq  = (const float*)d_in[4];
  const float* wk  = (const float*)d_in[5];
  const float* bk  = (const float*)d_in[6];
  const float* wv  = (const float*)d_in[7];
  const float* bv  = (const float*)d_in[8];
  const float* wo  = (const float*)d_in[9];
  const float* bo  = (const float*)d_in[10];
  const float* g1  = (const float*)d_in[11];
  const float* b1  = (const float*)d_in[12];
  const float* g2  = (const float*)d_in[13];
  const float* b2  = (const float*)d_in[14];
  const float* wf1 = (const float*)d_in[15];
  const float* bf1 = (const float*)d_in[16];
  const float* wf2 = (const float*)d_in[17];
  const float* bf2 = (const float*)d_in[18];
  float* out = (float*)d_out;

  float* ws    = (float*)d_ws;
  float* norm1 = ws;                    // 4096*256
  float* qb    = ws + 1 * 1048576;
  float* kb    = ws + 2 * 1048576;
  float* vb    = ws + 3 * 1048576;
  float* att   = ws + 4 * 1048576;
  float* hid2  = ws + 5 * 1048576;
  float* h2n   = ws + 6 * 1048576;
  float* ffa   = ws + 7 * 1048576;      // 4096*1024

  ln_kernel<<<NTOK / 4, 256, 0, stream>>>(hidden, g1, b1, norm1);

  dim3 gP(256 / 64, NTOK / 64);   // (4, 64)
  gemm_kernel<0,0><<<gP, 256, 0, stream>>>(norm1, wq, bq, nullptr, qb, NTOK, 256, 256);
  gemm_kernel<0,0><<<gP, 256, 0, stream>>>(norm1, wk, bk, nullptr, kb, NTOK, 256, 256);
  gemm_kernel<0,0><<<gP, 256, 0, stream>>>(norm1, wv, bv, nullptr, vb, NTOK, 256, 256);

  attn_kernel<<<dim3(NN / 64, NH, BB), 256, 0, stream>>>(qb, kb, vb, adjacency, att);

  gemm_kernel<0,1><<<gP, 256, 0, stream>>>(att, wo, bo, hidden, hid2, NTOK, 256, 256);

  ln_kernel<<<NTOK / 4, 256, 0, stream>>>(hid2, g2, b2, h2n);

  gemm_kernel<1,0><<<dim3(1024 / 64, NTOK / 64), 256, 0, stream>>>(h2n, wf1, bf1, nullptr, ffa, NTOK, 1024, 256);
  gemm_kernel<0,1><<<gP, 256, 0, stream>>>(ffa, wf2, bf2, hid2, out, NTOK, 256, 1024);
}

// Round 4
// 252.693 us; speedup vs baseline: 1.8946x; 1.8946x over previous
//
#include <hip/hip_runtime.h>
#include <math.h>

#define BB 2
#define NN 2048
#define HD 256
#define NH 8
#define DH 32
#define NTOK (BB*NN)   // 4096

typedef _Float16 h8 __attribute__((ext_vector_type(8)));
typedef _Float16 h4 __attribute__((ext_vector_type(4)));
typedef float fx4 __attribute__((ext_vector_type(4)));

// ---------------- LayerNorm: one wave per 256-wide row ----------------
__global__ __launch_bounds__(256) void ln_kernel(const float* __restrict__ x,
    const float* __restrict__ g, const float* __restrict__ bta,
    float* __restrict__ y)
{
  int row  = blockIdx.x * 4 + (threadIdx.x >> 6);
  int lane = threadIdx.x & 63;
  const float* xr = x + (size_t)row * HD + lane * 4;
  float4 v = *(const float4*)xr;
  float s = v.x + v.y + v.z + v.w;
  #pragma unroll
  for (int off = 32; off > 0; off >>= 1) s += __shfl_xor(s, off);
  float mu = s * (1.0f / HD);
  float dx0 = v.x - mu, dx1 = v.y - mu, dx2 = v.z - mu, dx3 = v.w - mu;
  float ss = dx0*dx0 + dx1*dx1 + dx2*dx2 + dx3*dx3;
  #pragma unroll
  for (int off = 32; off > 0; off >>= 1) ss += __shfl_xor(ss, off);
  float rinv = rsqrtf(ss * (1.0f / HD) + 1e-5f);
  float4 gv = *(const float4*)(g   + lane * 4);
  float4 bv = *(const float4*)(bta + lane * 4);
  float4 o;
  o.x = dx0 * rinv * gv.x + bv.x;
  o.y = dx1 * rinv * gv.y + bv.y;
  o.z = dx2 * rinv * gv.z + bv.z;
  o.w = dx3 * rinv * gv.w + bv.w;
  *(float4*)(y + (size_t)row * HD + lane * 4) = o;
}

// ---------------- fp32 tiled GEMM (unchanged this round) ----------------
template<int ACT, int RES>
__global__ __launch_bounds__(256) void gemm_kernel(const float* __restrict__ A,
    const float* __restrict__ W, const float* __restrict__ bias,
    const float* __restrict__ resid, float* __restrict__ C,
    int M, int N, int K)
{
  __shared__ float As[16][64];   // [k][m]
  __shared__ float Ws[16][64];   // [k][n]
  int t  = threadIdx.x;
  int tx = t & 15, ty = t >> 4;
  int m0 = blockIdx.y * 64, n0 = blockIdx.x * 64;
  float acc[4][4];
  #pragma unroll
  for (int i = 0; i < 4; i++)
    #pragma unroll
    for (int j = 0; j < 4; j++) acc[i][j] = 0.f;

  int arow = t >> 2, akp = (t & 3) * 4;
  int wkr  = t >> 4, wnp = (t & 15) * 4;

  for (int k0 = 0; k0 < K; k0 += 16) {
    __syncthreads();
    float4 av = *(const float4*)&A[(size_t)(m0 + arow) * K + k0 + akp];
    As[akp + 0][arow] = av.x; As[akp + 1][arow] = av.y;
    As[akp + 2][arow] = av.z; As[akp + 3][arow] = av.w;
    float4 wvv = *(const float4*)&W[(size_t)(k0 + wkr) * N + n0 + wnp];
    *(float4*)&Ws[wkr][wnp] = wvv;
    __syncthreads();
    #pragma unroll
    for (int kk = 0; kk < 16; kk++) {
      float4 a4 = *(const float4*)&As[kk][ty * 4];
      float4 b4 = *(const float4*)&Ws[kk][tx * 4];
      float aa[4] = {a4.x, a4.y, a4.z, a4.w};
      float bb[4] = {b4.x, b4.y, b4.z, b4.w};
      #pragma unroll
      for (int i = 0; i < 4; i++)
        #pragma unroll
        for (int j = 0; j < 4; j++) acc[i][j] += aa[i] * bb[j];
    }
  }

  #pragma unroll
  for (int i = 0; i < 4; i++) {
    int mm = m0 + ty * 4 + i;
    float4 o;
    float* op = &o.x;
    #pragma unroll
    for (int j = 0; j < 4; j++) {
      int nn = n0 + tx * 4 + j;
      float vv = acc[i][j] + bias[nn];
      if (ACT == 1) vv = 0.5f * vv * (1.0f + erff(vv * 0.70710678118654752f));
      if (RES)      vv += resid[(size_t)mm * N + nn];
      op[j] = vv;
    }
    *(float4*)&C[(size_t)mm * N + n0 + tx * 4] = o;
  }
}

// ---------------- MFMA flash attention (fp16 hi/lo split, S^T trick) ----------------
// Block: 4 waves, one (b, h, 64-row Q tile). Wave w: q-rows q0+w*16 .. +15.
// Lane l: m = l&15 (q-row within wave), g = l>>4.
// S^T tile = mfma(A=K_frag, B=Q_frag): D[row=kcol][col=qrow] -> lane holds
// kcols 4g+i of its own q-row -> softmax reduce = 2 shfl_xor (16,32).
// PV: O^T = mfma(A=V^T_frag(perm), B=P^T_frag): k-slot (g, j=4t+i) <-> kv = 16t+4g+i.
// NOTE: O (mfma output) is a FULL kv-sum per lane, but S is per-lane partial
// (8 of 32 kv per substep) -> must reduce S across lanes 16/32 at the end.
__global__ __launch_bounds__(256) void attn_mfma_kernel(
    const float* __restrict__ q, const float* __restrict__ k,
    const float* __restrict__ v, const float* __restrict__ adj,
    float* __restrict__ out)
{
  __shared__ _Float16 Ksh[64][40];   // [kv][dim]  stride 40 halves: conflict-free b128
  __shared__ _Float16 Ksl[64][40];
  __shared__ _Float16 Vth[32][76];   // [dim][kv]  stride 76 halves: conflict-free b64
  __shared__ _Float16 Vtl[32][76];

  const int b = blockIdx.z, h = blockIdx.y;
  const int q0 = blockIdx.x * 64;
  const int t = threadIdx.x;
  const int w = t >> 6, l = t & 63;
  const int m = l & 15, g = l >> 4;

  // --- Q fragment (pre-scaled by 1/sqrt(DH)), hi/lo split, loaded once ---
  const int qrow = q0 + w * 16 + m;
  h8 qh, ql;
  {
    const float* qp = q + ((size_t)(b * NN + qrow)) * HD + h * DH + g * 8;
    float4 x0 = *(const float4*)qp;
    float4 x1 = *(const float4*)(qp + 4);
    float xs[8] = {x0.x, x0.y, x0.z, x0.w, x1.x, x1.y, x1.z, x1.w};
    #pragma unroll
    for (int j = 0; j < 8; j++) {
      float xv = xs[j] * 0.17677669529663687f;
      _Float16 hi = (_Float16)xv;
      qh[j] = hi;
      ql[j] = (_Float16)(xv - (float)hi);
    }
  }

  fx4 ot0 = {0.f, 0.f, 0.f, 0.f};   // O^T dims  4g+i  (d 0..15)
  fx4 ot1 = {0.f, 0.f, 0.f, 0.f};   // O^T dims 16+4g+i
  float M = -3.0e38f, S = 0.0f;

  const float* adjrow = adj + ((size_t)(b * NN + qrow)) * NN;

  // staging-register prefetch (T14 async-stage split)
  const int krow = t >> 2, kd0 = (t & 3) * 8;   // K role
  const int rg = t >> 4, dp = t & 15;           // V role
  float4 kx0, kx1;
  float2 vr0, vr1, vr2, vr3;
  {
    const float* kp = k + ((size_t)(b * NN + 0 + krow)) * HD + h * DH + kd0;
    kx0 = *(const float4*)kp;  kx1 = *(const float4*)(kp + 4);
    const float* vp = v + ((size_t)(b * NN + 0 + rg * 4)) * HD + h * DH + dp * 2;
    vr0 = *(const float2*)vp;          vr1 = *(const float2*)(vp + HD);
    vr2 = *(const float2*)(vp + 2*HD); vr3 = *(const float2*)(vp + 3*HD);
  }

  for (int kt0 = 0; kt0 < NN; kt0 += 64) {
    __syncthreads();
    // ---- write staged regs -> LDS (hi/lo split at write time) ----
    {
      float xs[8] = {kx0.x, kx0.y, kx0.z, kx0.w, kx1.x, kx1.y, kx1.z, kx1.w};
      h8 hh, hl;
      #pragma unroll
      for (int j = 0; j < 8; j++) {
        _Float16 hi = (_Float16)xs[j];
        hh[j] = hi; hl[j] = (_Float16)(xs[j] - (float)hi);
      }
      *(h8*)&Ksh[krow][kd0] = hh;
      *(h8*)&Ksl[krow][kd0] = hl;
    }
    {
      #pragma unroll
      for (int dd = 0; dd < 2; dd++) {
        float vals[4] = { dd ? vr0.y : vr0.x, dd ? vr1.y : vr1.x,
                          dd ? vr2.y : vr2.x, dd ? vr3.y : vr3.x };
        h4 hh, hl;
        #pragma unroll
        for (int j = 0; j < 4; j++) {
          _Float16 hi = (_Float16)vals[j];
          hh[j] = hi; hl[j] = (_Float16)(vals[j] - (float)hi);
        }
        *(h4*)&Vth[dp * 2 + dd][rg * 4] = hh;
        *(h4*)&Vtl[dp * 2 + dd][rg * 4] = hl;
      }
    }
    __syncthreads();

    // ---- issue next tile's global loads (hidden under compute) ----
    if (kt0 + 64 < NN) {
      const float* kp = k + ((size_t)(b * NN + kt0 + 64 + krow)) * HD + h * DH + kd0;
      kx0 = *(const float4*)kp;  kx1 = *(const float4*)(kp + 4);
      const float* vp = v + ((size_t)(b * NN + kt0 + 64 + rg * 4)) * HD + h * DH + dp * 2;
      vr0 = *(const float2*)vp;          vr1 = *(const float2*)(vp + HD);
      vr2 = *(const float2*)(vp + 2*HD); vr3 = *(const float2*)(vp + 3*HD);
    }

    // ---- adjacency for both substeps (global, L3-resident) ----
    float4 adjv[2][2];
    #pragma unroll
    for (int ss = 0; ss < 2; ss++) {
      adjv[ss][0] = *(const float4*)(adjrow + kt0 + ss * 32 + g * 4);
      adjv[ss][1] = *(const float4*)(adjrow + kt0 + ss * 32 + 16 + g * 4);
    }

    // ---- two 32-kcol substeps ----
    #pragma unroll
    for (int ss = 0; ss < 2; ss++) {
      const int ksub = ss * 32;
      h8 kh0 = *(const h8*)&Ksh[ksub +      m][g * 8];
      h8 kl0 = *(const h8*)&Ksl[ksub +      m][g * 8];
      h8 kh1 = *(const h8*)&Ksh[ksub + 16 + m][g * 8];
      h8 kl1 = *(const h8*)&Ksl[ksub + 16 + m][g * 8];
      fx4 z = {0.f, 0.f, 0.f, 0.f};
      fx4 st0 = __builtin_amdgcn_mfma_f32_16x16x32_f16(kl0, qh, z, 0, 0, 0);
      st0 = __builtin_amdgcn_mfma_f32_16x16x32_f16(kh0, ql, st0, 0, 0, 0);
      st0 = __builtin_amdgcn_mfma_f32_16x16x32_f16(kh0, qh, st0, 0, 0, 0);
      fx4 st1 = __builtin_amdgcn_mfma_f32_16x16x32_f16(kl1, qh, z, 0, 0, 0);
      st1 = __builtin_amdgcn_mfma_f32_16x16x32_f16(kh1, ql, st1, 0, 0, 0);
      st1 = __builtin_amdgcn_mfma_f32_16x16x32_f16(kh1, qh, st1, 0, 0, 0);

      const float* a0 = (const float*)&adjv[ss][0];
      const float* a1 = (const float*)&adjv[ss][1];
      float lv[8];
      float tm = -3.0e38f;
      #pragma unroll
      for (int i = 0; i < 4; i++) {
        lv[i]     = st0[i] + 2.0f * a0[i] - 1.0f;
        lv[4 + i] = st1[i] + 2.0f * a1[i] - 1.0f;
        tm = fmaxf(tm, fmaxf(lv[i], lv[4 + i]));
      }
      tm = fmaxf(tm, __shfl_xor(tm, 16));
      tm = fmaxf(tm, __shfl_xor(tm, 32));
      float mnew = fmaxf(M, tm);
      float resc = __expf(M - mnew);
      M = mnew;
      S *= resc;
      ot0 *= resc;
      ot1 *= resc;
      float pv[8];
      #pragma unroll
      for (int i = 0; i < 4; i++) {
        pv[i]     = (0.25f + 0.75f * a0[i]) * __expf(lv[i]     - M);
        pv[4 + i] = (0.25f + 0.75f * a1[i]) * __expf(lv[4 + i] - M);
        S += pv[i] + pv[4 + i];
      }
      h8 ph, pl;
      #pragma unroll
      for (int j = 0; j < 8; j++) {
        _Float16 hi = (_Float16)pv[j];
        ph[j] = hi; pl[j] = (_Float16)(pv[j] - (float)hi);
      }
      // V^T fragments with matching k-slot permutation
      h4 t00 = *(const h4*)&Vth[m][ksub + g * 4];
      h4 t01 = *(const h4*)&Vth[m][ksub + 16 + g * 4];
      h4 s00 = *(const h4*)&Vtl[m][ksub + g * 4];
      h4 s01 = *(const h4*)&Vtl[m][ksub + 16 + g * 4];
      h4 t10 = *(const h4*)&Vth[16 + m][ksub + g * 4];
      h4 t11 = *(const h4*)&Vth[16 + m][ksub + 16 + g * 4];
      h4 s10 = *(const h4*)&Vtl[16 + m][ksub + g * 4];
      h4 s11 = *(const h4*)&Vtl[16 + m][ksub + 16 + g * 4];
      h8 vh0, vl0, vh1, vl1;
      #pragma unroll
      for (int j = 0; j < 4; j++) {
        vh0[j] = t00[j]; vh0[4 + j] = t01[j];
        vl0[j] = s00[j]; vl0[4 + j] = s01[j];
        vh1[j] = t10[j]; vh1[4 + j] = t11[j];
        vl1[j] = s10[j]; vl1[4 + j] = s11[j];
      }
      ot0 = __builtin_amdgcn_mfma_f32_16x16x32_f16(vl0, ph, ot0, 0, 0, 0);
      ot0 = __builtin_amdgcn_mfma_f32_16x16x32_f16(vh0, pl, ot0, 0, 0, 0);
      ot0 = __builtin_amdgcn_mfma_f32_16x16x32_f16(vh0, ph, ot0, 0, 0, 0);
      ot1 = __builtin_amdgcn_mfma_f32_16x16x32_f16(vl1, ph, ot1, 0, 0, 0);
      ot1 = __builtin_amdgcn_mfma_f32_16x16x32_f16(vh1, pl, ot1, 0, 0, 0);
      ot1 = __builtin_amdgcn_mfma_f32_16x16x32_f16(vh1, ph, ot1, 0, 0, 0);
    }
  }

  // ---- FIX: S is per-lane partial (8/32 kv per substep) -> reduce across
  // the 4 lanes sharing q-row m (l ^ 16, l ^ 32). O needs no reduce (mfma
  // already contracts the full kv range).
  S += __shfl_xor(S, 16);
  S += __shfl_xor(S, 32);

  // ---- normalize + store: O^T lane holds dims {4g+i, 16+4g+i} of row qrow ----
  float is = 1.0f / S;
  float4 o0, o1;
  o0.x = ot0[0] * is; o0.y = ot0[1] * is; o0.z = ot0[2] * is; o0.w = ot0[3] * is;
  o1.x = ot1[0] * is; o1.y = ot1[1] * is; o1.z = ot1[2] * is; o1.w = ot1[3] * is;
  float* op = out + ((size_t)(b * NN + qrow)) * HD + h * DH;
  *(float4*)(op + 4 * g) = o0;
  *(float4*)(op + 16 + 4 * g) = o1;
}

extern "C" void kernel_launch(void* const* d_in, const int* in_sizes, int n_in,
                              void* d_out, int out_size, void* d_ws, size_t ws_size,
                              hipStream_t stream)
{
  const float* hidden    = (const float*)d_in[0];
  const float* adjacency = (const float*)d_in[1];
  const float* wq  = (const float*)d_in[3];
  const float* bq  = (const float*)d_in[4];
  const float* wk  = (const float*)d_in[5];
  const float* bk  = (const float*)d_in[6];
  const float* wv  = (const float*)d_in[7];
  const float* bv  = (const float*)d_in[8];
  const float* wo  = (const float*)d_in[9];
  const float* bo  = (const float*)d_in[10];
  const float* g1  = (const float*)d_in[11];
  const float* b1  = (const float*)d_in[12];
  const float* g2  = (const float*)d_in[13];
  const float* b2  = (const float*)d_in[14];
  const float* wf1 = (const float*)d_in[15];
  const float* bf1 = (const float*)d_in[16];
  const float* wf2 = (const float*)d_in[17];
  const float* bf2 = (const float*)d_in[18];
  float* out = (float*)d_out;

  float* ws    = (float*)d_ws;
  float* norm1 = ws;
  float* qb    = ws + 1 * 1048576;
  float* kb    = ws + 2 * 1048576;
  float* vb    = ws + 3 * 1048576;
  float* att   = ws + 4 * 1048576;
  float* hid2  = ws + 5 * 1048576;
  float* h2n   = ws + 6 * 1048576;
  float* ffa   = ws + 7 * 1048576;

  ln_kernel<<<NTOK / 4, 256, 0, stream>>>(hidden, g1, b1, norm1);

  dim3 gP(256 / 64, NTOK / 64);
  gemm_kernel<0,0><<<gP, 256, 0, stream>>>(norm1, wq, bq, nullptr, qb, NTOK, 256, 256);
  gemm_kernel<0,0><<<gP, 256, 0, stream>>>(norm1, wk, bk, nullptr, kb, NTOK, 256, 256);
  gemm_kernel<0,0><<<gP, 256, 0, stream>>>(norm1, wv, bv, nullptr, vb, NTOK, 256, 256);

  attn_mfma_kernel<<<dim3(NN / 64, NH, BB), 256, 0, stream>>>(qb, kb, vb, adjacency, att);

  gemm_kernel<0,1><<<gP, 256, 0, stream>>>(att, wo, bo, hidden, hid2, NTOK, 256, 256);

  ln_kernel<<<NTOK / 4, 256, 0, stream>>>(hid2, g2, b2, h2n);

  gemm_kernel<1,0><<<dim3(1024 / 64, NTOK / 64), 256, 0, stream>>>(h2n, wf1, bf1, nullptr, ffa, NTOK, 1024, 256);
  gemm_kernel<0,1><<<gP, 256, 0, stream>>>(ffa, wf2, bf2, hid2, out, NTOK, 256, 1024);
}

// Round 5
// 234.119 us; speedup vs baseline: 2.0449x; 1.0793x over previous
//
#include <hip/hip_runtime.h>
#include <math.h>

#define BB 2
#define NN 2048
#define HD 256
#define NH 8
#define DH 32
#define NTOK (BB*NN)   // 4096
#define QKVLD 768      // fused qkv row stride

typedef _Float16 h8 __attribute__((ext_vector_type(8)));
typedef _Float16 h4 __attribute__((ext_vector_type(4)));
typedef float fx4 __attribute__((ext_vector_type(4)));

// ---------------- LayerNorm: one wave per 256-wide row ----------------
__global__ __launch_bounds__(256) void ln_kernel(const float* __restrict__ x,
    const float* __restrict__ g, const float* __restrict__ bta,
    float* __restrict__ y)
{
  int row  = blockIdx.x * 4 + (threadIdx.x >> 6);
  int lane = threadIdx.x & 63;
  const float* xr = x + (size_t)row * HD + lane * 4;
  float4 v = *(const float4*)xr;
  float s = v.x + v.y + v.z + v.w;
  #pragma unroll
  for (int off = 32; off > 0; off >>= 1) s += __shfl_xor(s, off);
  float mu = s * (1.0f / HD);
  float dx0 = v.x - mu, dx1 = v.y - mu, dx2 = v.z - mu, dx3 = v.w - mu;
  float ss = dx0*dx0 + dx1*dx1 + dx2*dx2 + dx3*dx3;
  #pragma unroll
  for (int off = 32; off > 0; off >>= 1) ss += __shfl_xor(ss, off);
  float rinv = rsqrtf(ss * (1.0f / HD) + 1e-5f);
  float4 gv = *(const float4*)(g   + lane * 4);
  float4 bv = *(const float4*)(bta + lane * 4);
  float4 o;
  o.x = dx0 * rinv * gv.x + bv.x;
  o.y = dx1 * rinv * gv.y + bv.y;
  o.z = dx2 * rinv * gv.z + bv.z;
  o.w = dx3 * rinv * gv.w + bv.w;
  *(float4*)(y + (size_t)row * HD + lane * 4) = o;
}

// ---------------- weight pre-transpose: W[K][N] f32 -> Wt_h/Wt_l [N][K] fp16 ----------------
__global__ __launch_bounds__(256) void transpose_w_kernel(const float* __restrict__ W,
    _Float16* __restrict__ Wh, _Float16* __restrict__ Wl,
    int Nw, int rowoff, int ldout)
{
  __shared__ float tile[32][33];
  int k0 = blockIdx.y * 32, n0 = blockIdx.x * 32;
  int c = threadIdx.x & 31, r = threadIdx.x >> 5;   // r 0..7
  #pragma unroll
  for (int i = 0; i < 4; i++)
    tile[r + i * 8][c] = W[(size_t)(k0 + r + i * 8) * Nw + n0 + c];
  __syncthreads();
  #pragma unroll
  for (int i = 0; i < 4; i++) {
    int n = r + i * 8;
    float x = tile[c][n];
    _Float16 hi = (_Float16)x;
    Wh[(size_t)(rowoff + n0 + n) * ldout + k0 + c] = hi;
    Wl[(size_t)(rowoff + n0 + n) * ldout + k0 + c] = (_Float16)(x - (float)hi);
  }
}

__global__ void concat3_kernel(const float* __restrict__ a, const float* __restrict__ b,
                               const float* __restrict__ c, float* __restrict__ o)
{
  int t = blockIdx.x * 256 + threadIdx.x;
  o[t] = (t < 256) ? a[t] : (t < 512) ? b[t - 256] : c[t - 512];
}

// ---------------- MFMA GEMM, direct-fragment (no LDS): C[M,N] = A[M,K] @ W[K,N] ----------------
// Wt_h/Wt_l are the PRE-TRANSPOSED fp16 hi/lo weights, [N][K] row-major.
// Block = 4 waves; wave w owns rows m0+w*16..+15, cols n0..n0+NT*16.
// Fragment mappings (HW-verified via attn): A-frag lane l: row=l&15, k=8*(l>>4)+j;
// B-frag lane l: col=l&15, k=8*(l>>4)+j;  D lane l: row=4*(l>>4)+i, col=l&15.
template<int KK, int NT, int ACT, int RES>
__global__ __launch_bounds__(256) void gemm_mfma_kernel(
    const float* __restrict__ A, const _Float16* __restrict__ Wh,
    const _Float16* __restrict__ Wl, const float* __restrict__ bias,
    const float* __restrict__ resid, float* __restrict__ C, int N)
{
  const int n0 = blockIdx.x * (NT * 16);
  const int m0 = blockIdx.y * 64;
  const int t = threadIdx.x, w = t >> 6, l = t & 63;
  const int ml = l & 15, g = l >> 4;
  const int mrow = m0 + w * 16 + ml;

  const float* ap = A + (size_t)mrow * KK + g * 8;
  const _Float16* whp[NT];
  const _Float16* wlp[NT];
  #pragma unroll
  for (int nt = 0; nt < NT; nt++) {
    int nrow = n0 + nt * 16 + ml;
    whp[nt] = Wh + (size_t)nrow * KK + g * 8;
    wlp[nt] = Wl + (size_t)nrow * KK + g * 8;
  }

  fx4 acc[NT];
  #pragma unroll
  for (int nt = 0; nt < NT; nt++) acc[nt] = (fx4){0.f, 0.f, 0.f, 0.f};

  #pragma unroll 4
  for (int k0 = 0; k0 < KK; k0 += 32) {
    float4 a0 = *(const float4*)(ap + k0);
    float4 a1 = *(const float4*)(ap + k0 + 4);
    float xs[8] = {a0.x, a0.y, a0.z, a0.w, a1.x, a1.y, a1.z, a1.w};
    h8 ah, al;
    #pragma unroll
    for (int j = 0; j < 8; j++) {
      _Float16 hi = (_Float16)xs[j];
      ah[j] = hi; al[j] = (_Float16)(xs[j] - (float)hi);
    }
    #pragma unroll
    for (int nt = 0; nt < NT; nt++) {
      h8 wh = *(const h8*)(whp[nt] + k0);
      h8 wl = *(const h8*)(wlp[nt] + k0);
      acc[nt] = __builtin_amdgcn_mfma_f32_16x16x32_f16(al, wh, acc[nt], 0, 0, 0);
      acc[nt] = __builtin_amdgcn_mfma_f32_16x16x32_f16(ah, wl, acc[nt], 0, 0, 0);
      acc[nt] = __builtin_amdgcn_mfma_f32_16x16x32_f16(ah, wh, acc[nt], 0, 0, 0);
    }
  }

  #pragma unroll
  for (int nt = 0; nt < NT; nt++) {
    int n = n0 + nt * 16 + ml;
    float bv = bias[n];
    #pragma unroll
    for (int i = 0; i < 4; i++) {
      int m = m0 + w * 16 + 4 * g + i;
      float vv = acc[nt][i] + bv;
      if (ACT == 1) vv = 0.5f * vv * (1.0f + erff(vv * 0.70710678118654752f));
      if (RES)      vv += resid[(size_t)m * N + n];
      C[(size_t)m * N + n] = vv;
    }
  }
}

// ---------------- MFMA flash attention (fp16 hi/lo split, S^T trick) ----------------
// Reads fused qkv[4096][768]: q at col 0, k at col 256, v at col 512.
__global__ __launch_bounds__(256) void attn_mfma_kernel(
    const float* __restrict__ qkv, const float* __restrict__ adj,
    float* __restrict__ out)
{
  __shared__ _Float16 Ksh[64][40];   // [kv][dim]  stride 40 halves
  __shared__ _Float16 Ksl[64][40];
  __shared__ _Float16 Vth[32][76];   // [dim][kv]  stride 76 halves
  __shared__ _Float16 Vtl[32][76];

  const int b = blockIdx.z, h = blockIdx.y;
  const int q0 = blockIdx.x * 64;
  const int t = threadIdx.x;
  const int w = t >> 6, l = t & 63;
  const int m = l & 15, g = l >> 4;

  const int qrow = q0 + w * 16 + m;
  h8 qh, ql;
  {
    const float* qp = qkv + ((size_t)(b * NN + qrow)) * QKVLD + h * DH + g * 8;
    float4 x0 = *(const float4*)qp;
    float4 x1 = *(const float4*)(qp + 4);
    float xs[8] = {x0.x, x0.y, x0.z, x0.w, x1.x, x1.y, x1.z, x1.w};
    #pragma unroll
    for (int j = 0; j < 8; j++) {
      float xv = xs[j] * 0.17677669529663687f;
      _Float16 hi = (_Float16)xv;
      qh[j] = hi;
      ql[j] = (_Float16)(xv - (float)hi);
    }
  }

  fx4 ot0 = {0.f, 0.f, 0.f, 0.f};
  fx4 ot1 = {0.f, 0.f, 0.f, 0.f};
  float M = -3.0e38f, S = 0.0f;

  const float* adjrow = adj + ((size_t)(b * NN + qrow)) * NN;

  const int krow = t >> 2, kd0 = (t & 3) * 8;   // K role
  const int rg = t >> 4, dp = t & 15;           // V role
  float4 kx0, kx1;
  float2 vr0, vr1, vr2, vr3;
  {
    const float* kp = qkv + ((size_t)(b * NN + 0 + krow)) * QKVLD + 256 + h * DH + kd0;
    kx0 = *(const float4*)kp;  kx1 = *(const float4*)(kp + 4);
    const float* vp = qkv + ((size_t)(b * NN + 0 + rg * 4)) * QKVLD + 512 + h * DH + dp * 2;
    vr0 = *(const float2*)vp;             vr1 = *(const float2*)(vp + QKVLD);
    vr2 = *(const float2*)(vp + 2*QKVLD); vr3 = *(const float2*)(vp + 3*QKVLD);
  }

  for (int kt0 = 0; kt0 < NN; kt0 += 64) {
    __syncthreads();
    {
      float xs[8] = {kx0.x, kx0.y, kx0.z, kx0.w, kx1.x, kx1.y, kx1.z, kx1.w};
      h8 hh, hl;
      #pragma unroll
      for (int j = 0; j < 8; j++) {
        _Float16 hi = (_Float16)xs[j];
        hh[j] = hi; hl[j] = (_Float16)(xs[j] - (float)hi);
      }
      *(h8*)&Ksh[krow][kd0] = hh;
      *(h8*)&Ksl[krow][kd0] = hl;
    }
    {
      #pragma unroll
      for (int dd = 0; dd < 2; dd++) {
        float vals[4] = { dd ? vr0.y : vr0.x, dd ? vr1.y : vr1.x,
                          dd ? vr2.y : vr2.x, dd ? vr3.y : vr3.x };
        h4 hh, hl;
        #pragma unroll
        for (int j = 0; j < 4; j++) {
          _Float16 hi = (_Float16)vals[j];
          hh[j] = hi; hl[j] = (_Float16)(vals[j] - (float)hi);
        }
        *(h4*)&Vth[dp * 2 + dd][rg * 4] = hh;
        *(h4*)&Vtl[dp * 2 + dd][rg * 4] = hl;
      }
    }
    __syncthreads();

    if (kt0 + 64 < NN) {
      const float* kp = qkv + ((size_t)(b * NN + kt0 + 64 + krow)) * QKVLD + 256 + h * DH + kd0;
      kx0 = *(const float4*)kp;  kx1 = *(const float4*)(kp + 4);
      const float* vp = qkv + ((size_t)(b * NN + kt0 + 64 + rg * 4)) * QKVLD + 512 + h * DH + dp * 2;
      vr0 = *(const float2*)vp;             vr1 = *(const float2*)(vp + QKVLD);
      vr2 = *(const float2*)(vp + 2*QKVLD); vr3 = *(const float2*)(vp + 3*QKVLD);
    }

    float4 adjv[2][2];
    #pragma unroll
    for (int ss = 0; ss < 2; ss++) {
      adjv[ss][0] = *(const float4*)(adjrow + kt0 + ss * 32 + g * 4);
      adjv[ss][1] = *(const float4*)(adjrow + kt0 + ss * 32 + 16 + g * 4);
    }

    #pragma unroll
    for (int ss = 0; ss < 2; ss++) {
      const int ksub = ss * 32;
      h8 kh0 = *(const h8*)&Ksh[ksub +      m][g * 8];
      h8 kl0 = *(const h8*)&Ksl[ksub +      m][g * 8];
      h8 kh1 = *(const h8*)&Ksh[ksub + 16 + m][g * 8];
      h8 kl1 = *(const h8*)&Ksl[ksub + 16 + m][g * 8];
      fx4 z = {0.f, 0.f, 0.f, 0.f};
      fx4 st0 = __builtin_amdgcn_mfma_f32_16x16x32_f16(kl0, qh, z, 0, 0, 0);
      st0 = __builtin_amdgcn_mfma_f32_16x16x32_f16(kh0, ql, st0, 0, 0, 0);
      st0 = __builtin_amdgcn_mfma_f32_16x16x32_f16(kh0, qh, st0, 0, 0, 0);
      fx4 st1 = __builtin_amdgcn_mfma_f32_16x16x32_f16(kl1, qh, z, 0, 0, 0);
      st1 = __builtin_amdgcn_mfma_f32_16x16x32_f16(kh1, ql, st1, 0, 0, 0);
      st1 = __builtin_amdgcn_mfma_f32_16x16x32_f16(kh1, qh, st1, 0, 0, 0);

      const float* a0 = (const float*)&adjv[ss][0];
      const float* a1 = (const float*)&adjv[ss][1];
      float lv[8];
      float tm = -3.0e38f;
      #pragma unroll
      for (int i = 0; i < 4; i++) {
        lv[i]     = st0[i] + 2.0f * a0[i] - 1.0f;
        lv[4 + i] = st1[i] + 2.0f * a1[i] - 1.0f;
        tm = fmaxf(tm, fmaxf(lv[i], lv[4 + i]));
      }
      tm = fmaxf(tm, __shfl_xor(tm, 16));
      tm = fmaxf(tm, __shfl_xor(tm, 32));
      float mnew = fmaxf(M, tm);
      float resc = __expf(M - mnew);
      M = mnew;
      S *= resc;
      ot0 *= resc;
      ot1 *= resc;
      float pv[8];
      #pragma unroll
      for (int i = 0; i < 4; i++) {
        pv[i]     = (0.25f + 0.75f * a0[i]) * __expf(lv[i]     - M);
        pv[4 + i] = (0.25f + 0.75f * a1[i]) * __expf(lv[4 + i] - M);
        S += pv[i] + pv[4 + i];
      }
      h8 ph, pl;
      #pragma unroll
      for (int j = 0; j < 8; j++) {
        _Float16 hi = (_Float16)pv[j];
        ph[j] = hi; pl[j] = (_Float16)(pv[j] - (float)hi);
      }
      h4 t00 = *(const h4*)&Vth[m][ksub + g * 4];
      h4 t01 = *(const h4*)&Vth[m][ksub + 16 + g * 4];
      h4 s00 = *(const h4*)&Vtl[m][ksub + g * 4];
      h4 s01 = *(const h4*)&Vtl[m][ksub + 16 + g * 4];
      h4 t10 = *(const h4*)&Vth[16 + m][ksub + g * 4];
      h4 t11 = *(const h4*)&Vth[16 + m][ksub + 16 + g * 4];
      h4 s10 = *(const h4*)&Vtl[16 + m][ksub + g * 4];
      h4 s11 = *(const h4*)&Vtl[16 + m][ksub + 16 + g * 4];
      h8 vh0, vl0, vh1, vl1;
      #pragma unroll
      for (int j = 0; j < 4; j++) {
        vh0[j] = t00[j]; vh0[4 + j] = t01[j];
        vl0[j] = s00[j]; vl0[4 + j] = s01[j];
        vh1[j] = t10[j]; vh1[4 + j] = t11[j];
        vl1[j] = s10[j]; vl1[4 + j] = s11[j];
      }
      ot0 = __builtin_amdgcn_mfma_f32_16x16x32_f16(vl0, ph, ot0, 0, 0, 0);
      ot0 = __builtin_amdgcn_mfma_f32_16x16x32_f16(vh0, pl, ot0, 0, 0, 0);
      ot0 = __builtin_amdgcn_mfma_f32_16x16x32_f16(vh0, ph, ot0, 0, 0, 0);
      ot1 = __builtin_amdgcn_mfma_f32_16x16x32_f16(vl1, ph, ot1, 0, 0, 0);
      ot1 = __builtin_amdgcn_mfma_f32_16x16x32_f16(vh1, pl, ot1, 0, 0, 0);
      ot1 = __builtin_amdgcn_mfma_f32_16x16x32_f16(vh1, ph, ot1, 0, 0, 0);
    }
  }

  // S is per-lane partial -> reduce across the 4 lanes sharing q-row m.
  S += __shfl_xor(S, 16);
  S += __shfl_xor(S, 32);

  float is = 1.0f / S;
  float4 o0, o1;
  o0.x = ot0[0] * is; o0.y = ot0[1] * is; o0.z = ot0[2] * is; o0.w = ot0[3] * is;
  o1.x = ot1[0] * is; o1.y = ot1[1] * is; o1.z = ot1[2] * is; o1.w = ot1[3] * is;
  float* op = out + ((size_t)(b * NN + qrow)) * HD + h * DH;
  *(float4*)(op + 4 * g) = o0;
  *(float4*)(op + 16 + 4 * g) = o1;
}

extern "C" void kernel_launch(void* const* d_in, const int* in_sizes, int n_in,
                              void* d_out, int out_size, void* d_ws, size_t ws_size,
                              hipStream_t stream)
{
  const float* hidden    = (const float*)d_in[0];
  const float* adjacency = (const float*)d_in[1];
  const float* wq  = (const float*)d_in[3];
  const float* bq  = (const float*)d_in[4];
  const float* wk  = (const float*)d_in[5];
  const float* bk  = (const float*)d_in[6];
  const float* wv  = (const float*)d_in[7];
  const float* bv  = (const float*)d_in[8];
  const float* wo  = (const float*)d_in[9];
  const float* bo  = (const float*)d_in[10];
  const float* g1  = (const float*)d_in[11];
  const float* b1  = (const float*)d_in[12];
  const float* g2  = (const float*)d_in[13];
  const float* b2  = (const float*)d_in[14];
  const float* wf1 = (const float*)d_in[15];
  const float* bf1 = (const float*)d_in[16];
  const float* wf2 = (const float*)d_in[17];
  const float* bf2 = (const float*)d_in[18];
  float* out = (float*)d_out;

  char* base = (char*)d_ws;
  const size_t MB = 1024 * 1024;
  float* norm1 = (float*)(base);            // 4MB  (reused as h2n after attn)
  float* qkv   = (float*)(base + 4*MB);     // 12MB: [4096][768]
  float* att   = (float*)(base + 16*MB);    // 4MB
  float* hid2  = (float*)(base + 20*MB);    // 4MB
  float* ffa   = (float*)(base + 24*MB);    // 16MB -> ends 40MB
  float* h2n   = norm1;
  _Float16* wtb = (_Float16*)(base + 40*MB);
  _Float16* WtQKVh = wtb; wtb += 768 * 256;
  _Float16* WtQKVl = wtb; wtb += 768 * 256;
  _Float16* WtOh   = wtb; wtb += 256 * 256;
  _Float16* WtOl   = wtb; wtb += 256 * 256;
  _Float16* WtF1h  = wtb; wtb += 1024 * 256;
  _Float16* WtF1l  = wtb; wtb += 1024 * 256;
  _Float16* WtF2h  = wtb; wtb += 256 * 1024;
  _Float16* WtF2l  = wtb; wtb += 256 * 1024;
  float* biasqkv = (float*)(base + 43*MB);  // 768 floats

  // --- weight pre-transposition (f32 -> fp16 hi/lo, [N][K]) ---
  transpose_w_kernel<<<dim3(8, 8),  256, 0, stream>>>(wq,  WtQKVh, WtQKVl, 256,    0,  256);
  transpose_w_kernel<<<dim3(8, 8),  256, 0, stream>>>(wk,  WtQKVh, WtQKVl, 256,  256,  256);
  transpose_w_kernel<<<dim3(8, 8),  256, 0, stream>>>(wv,  WtQKVh, WtQKVl, 256,  512,  256);
  transpose_w_kernel<<<dim3(8, 8),  256, 0, stream>>>(wo,  WtOh,   WtOl,   256,    0,  256);
  transpose_w_kernel<<<dim3(32, 8), 256, 0, stream>>>(wf1, WtF1h,  WtF1l,  1024,   0,  256);
  transpose_w_kernel<<<dim3(8, 32), 256, 0, stream>>>(wf2, WtF2h,  WtF2l,  256,    0, 1024);
  concat3_kernel<<<3, 256, 0, stream>>>(bq, bk, bv, biasqkv);

  ln_kernel<<<NTOK / 4, 256, 0, stream>>>(hidden, g1, b1, norm1);

  // fused QKV: [4096][256] @ [256][768] -> qkv [4096][768]
  gemm_mfma_kernel<256, 4, 0, 0><<<dim3(12, 64), 256, 0, stream>>>(
      norm1, WtQKVh, WtQKVl, biasqkv, nullptr, qkv, QKVLD);

  attn_mfma_kernel<<<dim3(NN / 64, NH, BB), 256, 0, stream>>>(qkv, adjacency, att);

  gemm_mfma_kernel<256, 2, 0, 1><<<dim3(8, 64), 256, 0, stream>>>(
      att, WtOh, WtOl, bo, hidden, hid2, 256);

  ln_kernel<<<NTOK / 4, 256, 0, stream>>>(hid2, g2, b2, h2n);

  gemm_mfma_kernel<256, 4, 1, 0><<<dim3(16, 64), 256, 0, stream>>>(
      h2n, WtF1h, WtF1l, bf1, nullptr, ffa, 1024);

  gemm_mfma_kernel<1024, 2, 0, 1><<<dim3(8, 64), 256, 0, stream>>>(
      ffa, WtF2h, WtF2l, bf2, hid2, out, 256);
}

// Round 6
// 210.089 us; speedup vs baseline: 2.2788x; 1.1144x over previous
//
#include <hip/hip_runtime.h>
#include <math.h>

#define BB 2
#define NN 2048
#define HD 256
#define NH 8
#define DH 32
#define NTOK (BB*NN)   // 4096
#define QKVLD 768      // fused qkv row stride

typedef _Float16 h8 __attribute__((ext_vector_type(8)));
typedef _Float16 h4 __attribute__((ext_vector_type(4)));
typedef float fx4 __attribute__((ext_vector_type(4)));

// ---------------- LayerNorm: one wave per 256-wide row ----------------
__global__ __launch_bounds__(256) void ln_kernel(const float* __restrict__ x,
    const float* __restrict__ g, const float* __restrict__ bta,
    float* __restrict__ y)
{
  int row  = blockIdx.x * 4 + (threadIdx.x >> 6);
  int lane = threadIdx.x & 63;
  const float* xr = x + (size_t)row * HD + lane * 4;
  float4 v = *(const float4*)xr;
  float s = v.x + v.y + v.z + v.w;
  #pragma unroll
  for (int off = 32; off > 0; off >>= 1) s += __shfl_xor(s, off);
  float mu = s * (1.0f / HD);
  float dx0 = v.x - mu, dx1 = v.y - mu, dx2 = v.z - mu, dx3 = v.w - mu;
  float ss = dx0*dx0 + dx1*dx1 + dx2*dx2 + dx3*dx3;
  #pragma unroll
  for (int off = 32; off > 0; off >>= 1) ss += __shfl_xor(ss, off);
  float rinv = rsqrtf(ss * (1.0f / HD) + 1e-5f);
  float4 gv = *(const float4*)(g   + lane * 4);
  float4 bv = *(const float4*)(bta + lane * 4);
  float4 o;
  o.x = dx0 * rinv * gv.x + bv.x;
  o.y = dx1 * rinv * gv.y + bv.y;
  o.z = dx2 * rinv * gv.z + bv.z;
  o.w = dx3 * rinv * gv.w + bv.w;
  *(float4*)(y + (size_t)row * HD + lane * 4) = o;
}

// ---------------- weight pre-transpose: W[K][N] f32 -> Wt_h/Wt_l [N][K] fp16 ----------------
__global__ __launch_bounds__(256) void transpose_w_kernel(const float* __restrict__ W,
    _Float16* __restrict__ Wh, _Float16* __restrict__ Wl,
    int Nw, int rowoff, int ldout)
{
  __shared__ float tile[32][33];
  int k0 = blockIdx.y * 32, n0 = blockIdx.x * 32;
  int c = threadIdx.x & 31, r = threadIdx.x >> 5;   // r 0..7
  #pragma unroll
  for (int i = 0; i < 4; i++)
    tile[r + i * 8][c] = W[(size_t)(k0 + r + i * 8) * Nw + n0 + c];
  __syncthreads();
  #pragma unroll
  for (int i = 0; i < 4; i++) {
    int n = r + i * 8;
    float x = tile[c][n];
    _Float16 hi = (_Float16)x;
    Wh[(size_t)(rowoff + n0 + n) * ldout + k0 + c] = hi;
    Wl[(size_t)(rowoff + n0 + n) * ldout + k0 + c] = (_Float16)(x - (float)hi);
  }
}

__global__ void concat3_kernel(const float* __restrict__ a, const float* __restrict__ b,
                               const float* __restrict__ c, float* __restrict__ o)
{
  int t = blockIdx.x * 256 + threadIdx.x;
  o[t] = (t < 256) ? a[t] : (t < 512) ? b[t - 256] : c[t - 512];
}

// ---------------- MFMA GEMM, direct-fragment (no LDS): C[M,N] = A[M,K] @ W[K,N] ----------------
template<int KK, int NT, int ACT, int RES>
__global__ __launch_bounds__(256) void gemm_mfma_kernel(
    const float* __restrict__ A, const _Float16* __restrict__ Wh,
    const _Float16* __restrict__ Wl, const float* __restrict__ bias,
    const float* __restrict__ resid, float* __restrict__ C, int N)
{
  const int n0 = blockIdx.x * (NT * 16);
  const int m0 = blockIdx.y * 64;
  const int t = threadIdx.x, w = t >> 6, l = t & 63;
  const int ml = l & 15, g = l >> 4;
  const int mrow = m0 + w * 16 + ml;

  const float* ap = A + (size_t)mrow * KK + g * 8;
  const _Float16* whp[NT];
  const _Float16* wlp[NT];
  #pragma unroll
  for (int nt = 0; nt < NT; nt++) {
    int nrow = n0 + nt * 16 + ml;
    whp[nt] = Wh + (size_t)nrow * KK + g * 8;
    wlp[nt] = Wl + (size_t)nrow * KK + g * 8;
  }

  fx4 acc[NT];
  #pragma unroll
  for (int nt = 0; nt < NT; nt++) acc[nt] = (fx4){0.f, 0.f, 0.f, 0.f};

  #pragma unroll 4
  for (int k0 = 0; k0 < KK; k0 += 32) {
    float4 a0 = *(const float4*)(ap + k0);
    float4 a1 = *(const float4*)(ap + k0 + 4);
    float xs[8] = {a0.x, a0.y, a0.z, a0.w, a1.x, a1.y, a1.z, a1.w};
    h8 ah, al;
    #pragma unroll
    for (int j = 0; j < 8; j++) {
      _Float16 hi = (_Float16)xs[j];
      ah[j] = hi; al[j] = (_Float16)(xs[j] - (float)hi);
    }
    #pragma unroll
    for (int nt = 0; nt < NT; nt++) {
      h8 wh = *(const h8*)(whp[nt] + k0);
      h8 wl = *(const h8*)(wlp[nt] + k0);
      acc[nt] = __builtin_amdgcn_mfma_f32_16x16x32_f16(al, wh, acc[nt], 0, 0, 0);
      acc[nt] = __builtin_amdgcn_mfma_f32_16x16x32_f16(ah, wl, acc[nt], 0, 0, 0);
      acc[nt] = __builtin_amdgcn_mfma_f32_16x16x32_f16(ah, wh, acc[nt], 0, 0, 0);
    }
  }

  #pragma unroll
  for (int nt = 0; nt < NT; nt++) {
    int n = n0 + nt * 16 + ml;
    float bv = bias[n];
    #pragma unroll
    for (int i = 0; i < 4; i++) {
      int m = m0 + w * 16 + 4 * g + i;
      float vv = acc[nt][i] + bv;
      if (ACT == 1) vv = 0.5f * vv * (1.0f + erff(vv * 0.70710678118654752f));
      if (RES)      vv += resid[(size_t)m * N + n];
      C[(size_t)m * N + n] = vv;
    }
  }
}

// ---------------- MFMA flash attention: pure fp16, 2-way SPLIT-KV ----------------
// grid (NN/64, NH, BB*2); z = b*2 + half; each block does kv in [half*1024, half*1024+1024).
// Writes UNNORMALIZED O^T partial + per-row (M, S) to workspace; combine kernel merges.
__global__ __launch_bounds__(256) void attn_mfma_kernel(
    const float* __restrict__ qkv, const float* __restrict__ adj,
    float* __restrict__ Opart, float* __restrict__ Mpart, float* __restrict__ Spart)
{
  __shared__ _Float16 Ksh[64][40];   // [kv][dim]
  __shared__ _Float16 Vth[32][76];   // [dim][kv]

  const int z = blockIdx.z;
  const int b = z >> 1, half = z & 1;
  const int h = blockIdx.y;
  const int q0 = blockIdx.x * 64;
  const int t = threadIdx.x;
  const int w = t >> 6, l = t & 63;
  const int m = l & 15, g = l >> 4;
  const int kvbase = half * (NN / 2);

  const int qrow = q0 + w * 16 + m;
  h8 qh;
  {
    const float* qp = qkv + ((size_t)(b * NN + qrow)) * QKVLD + h * DH + g * 8;
    float4 x0 = *(const float4*)qp;
    float4 x1 = *(const float4*)(qp + 4);
    float xs[8] = {x0.x, x0.y, x0.z, x0.w, x1.x, x1.y, x1.z, x1.w};
    #pragma unroll
    for (int j = 0; j < 8; j++) qh[j] = (_Float16)(xs[j] * 0.17677669529663687f);
  }

  fx4 ot0 = {0.f, 0.f, 0.f, 0.f};
  fx4 ot1 = {0.f, 0.f, 0.f, 0.f};
  float M = -3.0e38f, S = 0.0f;

  const float* adjrow = adj + ((size_t)(b * NN + qrow)) * NN;

  const int krow = t >> 2, kd0 = (t & 3) * 8;   // K staging role
  const int rg = t >> 4, dp = t & 15;           // V staging role
  float4 kx0, kx1;
  float2 vr0, vr1, vr2, vr3;
  {
    const float* kp = qkv + ((size_t)(b * NN + kvbase + krow)) * QKVLD + 256 + h * DH + kd0;
    kx0 = *(const float4*)kp;  kx1 = *(const float4*)(kp + 4);
    const float* vp = qkv + ((size_t)(b * NN + kvbase + rg * 4)) * QKVLD + 512 + h * DH + dp * 2;
    vr0 = *(const float2*)vp;             vr1 = *(const float2*)(vp + QKVLD);
    vr2 = *(const float2*)(vp + 2*QKVLD); vr3 = *(const float2*)(vp + 3*QKVLD);
  }

  for (int kt0 = kvbase; kt0 < kvbase + NN / 2; kt0 += 64) {
    __syncthreads();
    {
      float xs[8] = {kx0.x, kx0.y, kx0.z, kx0.w, kx1.x, kx1.y, kx1.z, kx1.w};
      h8 hh;
      #pragma unroll
      for (int j = 0; j < 8; j++) hh[j] = (_Float16)xs[j];
      *(h8*)&Ksh[krow][kd0] = hh;
    }
    {
      #pragma unroll
      for (int dd = 0; dd < 2; dd++) {
        float vals[4] = { dd ? vr0.y : vr0.x, dd ? vr1.y : vr1.x,
                          dd ? vr2.y : vr2.x, dd ? vr3.y : vr3.x };
        h4 hh;
        #pragma unroll
        for (int j = 0; j < 4; j++) hh[j] = (_Float16)vals[j];
        *(h4*)&Vth[dp * 2 + dd][rg * 4] = hh;
      }
    }
    __syncthreads();

    if (kt0 + 64 < kvbase + NN / 2) {
      const float* kp = qkv + ((size_t)(b * NN + kt0 + 64 + krow)) * QKVLD + 256 + h * DH + kd0;
      kx0 = *(const float4*)kp;  kx1 = *(const float4*)(kp + 4);
      const float* vp = qkv + ((size_t)(b * NN + kt0 + 64 + rg * 4)) * QKVLD + 512 + h * DH + dp * 2;
      vr0 = *(const float2*)vp;             vr1 = *(const float2*)(vp + QKVLD);
      vr2 = *(const float2*)(vp + 2*QKVLD); vr3 = *(const float2*)(vp + 3*QKVLD);
    }

    float4 adjv[2][2];
    #pragma unroll
    for (int ss = 0; ss < 2; ss++) {
      adjv[ss][0] = *(const float4*)(adjrow + kt0 + ss * 32 + g * 4);
      adjv[ss][1] = *(const float4*)(adjrow + kt0 + ss * 32 + 16 + g * 4);
    }

    #pragma unroll
    for (int ss = 0; ss < 2; ss++) {
      const int ksub = ss * 32;
      h8 kh0 = *(const h8*)&Ksh[ksub +      m][g * 8];
      h8 kh1 = *(const h8*)&Ksh[ksub + 16 + m][g * 8];
      fx4 z4 = {0.f, 0.f, 0.f, 0.f};
      fx4 st0 = __builtin_amdgcn_mfma_f32_16x16x32_f16(kh0, qh, z4, 0, 0, 0);
      fx4 st1 = __builtin_amdgcn_mfma_f32_16x16x32_f16(kh1, qh, z4, 0, 0, 0);

      const float* a0 = (const float*)&adjv[ss][0];
      const float* a1 = (const float*)&adjv[ss][1];
      float lv[8];
      float tm = -3.0e38f;
      #pragma unroll
      for (int i = 0; i < 4; i++) {
        lv[i]     = st0[i] + 2.0f * a0[i] - 1.0f;
        lv[4 + i] = st1[i] + 2.0f * a1[i] - 1.0f;
        tm = fmaxf(tm, fmaxf(lv[i], lv[4 + i]));
      }
      tm = fmaxf(tm, __shfl_xor(tm, 16));
      tm = fmaxf(tm, __shfl_xor(tm, 32));
      float mnew = fmaxf(M, tm);
      float resc = __expf(M - mnew);
      M = mnew;
      S *= resc;
      ot0 *= resc;
      ot1 *= resc;
      float pv[8];
      #pragma unroll
      for (int i = 0; i < 4; i++) {
        pv[i]     = (0.25f + 0.75f * a0[i]) * __expf(lv[i]     - M);
        pv[4 + i] = (0.25f + 0.75f * a1[i]) * __expf(lv[4 + i] - M);
        S += pv[i] + pv[4 + i];
      }
      h8 ph;
      #pragma unroll
      for (int j = 0; j < 8; j++) ph[j] = (_Float16)pv[j];

      h4 t00 = *(const h4*)&Vth[m][ksub + g * 4];
      h4 t01 = *(const h4*)&Vth[m][ksub + 16 + g * 4];
      h4 t10 = *(const h4*)&Vth[16 + m][ksub + g * 4];
      h4 t11 = *(const h4*)&Vth[16 + m][ksub + 16 + g * 4];
      h8 vh0, vh1;
      #pragma unroll
      for (int j = 0; j < 4; j++) {
        vh0[j] = t00[j]; vh0[4 + j] = t01[j];
        vh1[j] = t10[j]; vh1[4 + j] = t11[j];
      }
      ot0 = __builtin_amdgcn_mfma_f32_16x16x32_f16(vh0, ph, ot0, 0, 0, 0);
      ot1 = __builtin_amdgcn_mfma_f32_16x16x32_f16(vh1, ph, ot1, 0, 0, 0);
    }
  }

  // reduce the per-lane partial denominator across the 4 lanes of each q-row
  S += __shfl_xor(S, 16);
  S += __shfl_xor(S, 32);

  // store unnormalized partials
  size_t prow = ((size_t)(z * NH + h)) * NN + qrow;
  float* po = Opart + prow * 32;
  float4 o0 = make_float4(ot0[0], ot0[1], ot0[2], ot0[3]);
  float4 o1 = make_float4(ot1[0], ot1[1], ot1[2], ot1[3]);
  *(float4*)(po + 4 * g) = o0;
  *(float4*)(po + 16 + 4 * g) = o1;
  if (g == 0) { Mpart[prow] = M; Spart[prow] = S; }
}

// ---------------- combine the two KV halves ----------------
__global__ __launch_bounds__(256) void attn_combine_kernel(
    const float* __restrict__ Opart, const float* __restrict__ Mpart,
    const float* __restrict__ Spart, float* __restrict__ att)
{
  int idx = blockIdx.x * 256 + threadIdx.x;   // BB*NH*NN*8 total
  int dg  = idx & 7;
  int rowid = idx >> 3;                        // (b*NH+h)*NN + qrow
  int qrow = rowid & (NN - 1);
  int bh = rowid >> 11;
  int b = bh >> 3, h = bh & 7;
  size_t p0 = ((size_t)((b * 2 + 0) * NH + h)) * NN + qrow;
  size_t p1 = ((size_t)((b * 2 + 1) * NH + h)) * NN + qrow;
  float m0 = Mpart[p0], m1 = Mpart[p1];
  float s0 = Spart[p0], s1 = Spart[p1];
  float mm = fmaxf(m0, m1);
  float e0 = __expf(m0 - mm), e1 = __expf(m1 - mm);
  float is = 1.0f / (s0 * e0 + s1 * e1);
  float4 o0 = *(const float4*)(Opart + p0 * 32 + dg * 4);
  float4 o1 = *(const float4*)(Opart + p1 * 32 + dg * 4);
  float4 o;
  o.x = (o0.x * e0 + o1.x * e1) * is;
  o.y = (o0.y * e0 + o1.y * e1) * is;
  o.z = (o0.z * e0 + o1.z * e1) * is;
  o.w = (o0.w * e0 + o1.w * e1) * is;
  *(float4*)(att + ((size_t)(b * NN + qrow)) * HD + h * DH + dg * 4) = o;
}

extern "C" void kernel_launch(void* const* d_in, const int* in_sizes, int n_in,
                              void* d_out, int out_size, void* d_ws, size_t ws_size,
                              hipStream_t stream)
{
  const float* hidden    = (const float*)d_in[0];
  const float* adjacency = (const float*)d_in[1];
  const float* wq  = (const float*)d_in[3];
  const float* bq  = (const float*)d_in[4];
  const float* wk  = (const float*)d_in[5];
  const float* bk  = (const float*)d_in[6];
  const float* wv  = (const float*)d_in[7];
  const float* bv  = (const float*)d_in[8];
  const float* wo  = (const float*)d_in[9];
  const float* bo  = (const float*)d_in[10];
  const float* g1  = (const float*)d_in[11];
  const float* b1  = (const float*)d_in[12];
  const float* g2  = (const float*)d_in[13];
  const float* b2  = (const float*)d_in[14];
  const float* wf1 = (const float*)d_in[15];
  const float* bf1 = (const float*)d_in[16];
  const float* wf2 = (const float*)d_in[17];
  const float* bf2 = (const float*)d_in[18];
  float* out = (float*)d_out;

  char* base = (char*)d_ws;
  const size_t MB = 1024 * 1024;
  float* norm1 = (float*)(base);            // [0,4) MB   (reused as h2n)
  float* qkv   = (float*)(base + 4*MB);     // [4,16) MB: [4096][768]
  float* att   = (float*)(base + 16*MB);    // [16,20) MB
  float* hid2  = (float*)(base + 20*MB);    // [20,24) MB
  float* ffa   = (float*)(base + 24*MB);    // [24,40) MB (FF1 out; overlaid below)
  // attn partials live in the ffa region (dead until FF1 runs):
  float* Opart = (float*)(base + 24*MB);    // 8 MB: [4][8][2048][32]
  float* Mpart = (float*)(base + 32*MB);    // 256 KB
  float* Spart = (float*)(base + 33*MB);    // 256 KB
  float* h2n   = norm1;
  _Float16* wtb = (_Float16*)(base + 40*MB);
  _Float16* WtQKVh = wtb; wtb += 768 * 256;
  _Float16* WtQKVl = wtb; wtb += 768 * 256;
  _Float16* WtOh   = wtb; wtb += 256 * 256;
  _Float16* WtOl   = wtb; wtb += 256 * 256;
  _Float16* WtF1h  = wtb; wtb += 1024 * 256;
  _Float16* WtF1l  = wtb; wtb += 1024 * 256;
  _Float16* WtF2h  = wtb; wtb += 256 * 1024;
  _Float16* WtF2l  = wtb; wtb += 256 * 1024;
  float* biasqkv = (float*)(base + 43*MB);  // 768 floats

  transpose_w_kernel<<<dim3(8, 8),  256, 0, stream>>>(wq,  WtQKVh, WtQKVl, 256,    0,  256);
  transpose_w_kernel<<<dim3(8, 8),  256, 0, stream>>>(wk,  WtQKVh, WtQKVl, 256,  256,  256);
  transpose_w_kernel<<<dim3(8, 8),  256, 0, stream>>>(wv,  WtQKVh, WtQKVl, 256,  512,  256);
  transpose_w_kernel<<<dim3(8, 8),  256, 0, stream>>>(wo,  WtOh,   WtOl,   256,    0,  256);
  transpose_w_kernel<<<dim3(32, 8), 256, 0, stream>>>(wf1, WtF1h,  WtF1l,  1024,   0,  256);
  transpose_w_kernel<<<dim3(8, 32), 256, 0, stream>>>(wf2, WtF2h,  WtF2l,  256,    0, 1024);
  concat3_kernel<<<3, 256, 0, stream>>>(bq, bk, bv, biasqkv);

  ln_kernel<<<NTOK / 4, 256, 0, stream>>>(hidden, g1, b1, norm1);

  gemm_mfma_kernel<256, 4, 0, 0><<<dim3(12, 64), 256, 0, stream>>>(
      norm1, WtQKVh, WtQKVl, biasqkv, nullptr, qkv, QKVLD);

  attn_mfma_kernel<<<dim3(NN / 64, NH, BB * 2), 256, 0, stream>>>(
      qkv, adjacency, Opart, Mpart, Spart);
  attn_combine_kernel<<<(BB * NH * NN * 8) / 256, 256, 0, stream>>>(
      Opart, Mpart, Spart, att);

  gemm_mfma_kernel<256, 2, 0, 1><<<dim3(8, 64), 256, 0, stream>>>(
      att, WtOh, WtOl, bo, hidden, hid2, 256);

  ln_kernel<<<NTOK / 4, 256, 0, stream>>>(hid2, g2, b2, h2n);

  gemm_mfma_kernel<256, 4, 1, 0><<<dim3(16, 64), 256, 0, stream>>>(
      h2n, WtF1h, WtF1l, bf1, nullptr, ffa, 1024);

  gemm_mfma_kernel<1024, 2, 0, 1><<<dim3(8, 64), 256, 0, stream>>>(
      ffa, WtF2h, WtF2l, bf2, hid2, out, 256);
}

// Round 7
// 202.091 us; speedup vs baseline: 2.3689x; 1.0396x over previous
//
#include <hip/hip_runtime.h>
#include <math.h>

#define BB 2
#define NN 2048
#define HD 256
#define NH 8
#define DH 32
#define NTOK (BB*NN)   // 4096
#define QKVLD 768      // fused qkv row stride (fp16)

typedef _Float16 h8 __attribute__((ext_vector_type(8)));
typedef _Float16 h4 __attribute__((ext_vector_type(4)));
typedef float fx4 __attribute__((ext_vector_type(4)));

#define LOG2E 1.4426950408889634f
#define SQ_LOG2 0.25503486f   // log2(e)/sqrt(32), folded into wq/bq

// ---------------- LayerNorm: f32 in -> fp16 hi/lo out ----------------
__global__ __launch_bounds__(256) void ln_kernel(const float* __restrict__ x,
    const float* __restrict__ g, const float* __restrict__ bta,
    _Float16* __restrict__ yh, _Float16* __restrict__ yl)
{
  int row  = blockIdx.x * 4 + (threadIdx.x >> 6);
  int lane = threadIdx.x & 63;
  const float* xr = x + (size_t)row * HD + lane * 4;
  float4 v = *(const float4*)xr;
  float s = v.x + v.y + v.z + v.w;
  #pragma unroll
  for (int off = 32; off > 0; off >>= 1) s += __shfl_xor(s, off);
  float mu = s * (1.0f / HD);
  float dx0 = v.x - mu, dx1 = v.y - mu, dx2 = v.z - mu, dx3 = v.w - mu;
  float ss = dx0*dx0 + dx1*dx1 + dx2*dx2 + dx3*dx3;
  #pragma unroll
  for (int off = 32; off > 0; off >>= 1) ss += __shfl_xor(ss, off);
  float rinv = rsqrtf(ss * (1.0f / HD) + 1e-5f);
  float4 gv = *(const float4*)(g   + lane * 4);
  float4 bv = *(const float4*)(bta + lane * 4);
  float o[4];
  o[0] = dx0 * rinv * gv.x + bv.x;
  o[1] = dx1 * rinv * gv.y + bv.y;
  o[2] = dx2 * rinv * gv.z + bv.z;
  o[3] = dx3 * rinv * gv.w + bv.w;
  h4 hh, hl;
  #pragma unroll
  for (int j = 0; j < 4; j++) {
    _Float16 hi = (_Float16)o[j];
    hh[j] = hi; hl[j] = (_Float16)(o[j] - (float)hi);
  }
  *(h4*)(yh + (size_t)row * HD + lane * 4) = hh;
  *(h4*)(yl + (size_t)row * HD + lane * 4) = hl;
}

// ---------------- weight pre-transpose: W[K][N] f32 -> Wt_h/Wt_l [N][K] fp16 (scaled) ------
__global__ __launch_bounds__(256) void transpose_w_kernel(const float* __restrict__ W,
    _Float16* __restrict__ Wh, _Float16* __restrict__ Wl,
    int Nw, int rowoff, int ldout, float scale)
{
  __shared__ float tile[32][33];
  int k0 = blockIdx.y * 32, n0 = blockIdx.x * 32;
  int c = threadIdx.x & 31, r = threadIdx.x >> 5;   // r 0..7
  #pragma unroll
  for (int i = 0; i < 4; i++)
    tile[r + i * 8][c] = W[(size_t)(k0 + r + i * 8) * Nw + n0 + c];
  __syncthreads();
  #pragma unroll
  for (int i = 0; i < 4; i++) {
    int n = r + i * 8;
    float x = tile[c][n] * scale;
    _Float16 hi = (_Float16)x;
    Wh[(size_t)(rowoff + n0 + n) * ldout + k0 + c] = hi;
    Wl[(size_t)(rowoff + n0 + n) * ldout + k0 + c] = (_Float16)(x - (float)hi);
  }
}

__global__ void concat3_kernel(const float* __restrict__ a, const float* __restrict__ b,
                               const float* __restrict__ c, float* __restrict__ o)
{
  int t = blockIdx.x * 256 + threadIdx.x;
  o[t] = (t < 256) ? a[t] * SQ_LOG2 : (t < 512) ? b[t - 256] : c[t - 512];
}

// ---------------- MFMA GEMM, direct-fragment, fp16 hi/lo A and W ----------------
// OM: 0 = f32 C (+resid); 1 = fp16 hi/lo pair out; 2 = qkv mode (fp16 single; V transposed)
template<int KK, int NT, int ACT, int RES, int OM>
__global__ __launch_bounds__(256) void gemm_mfma_kernel(
    const _Float16* __restrict__ Ah, const _Float16* __restrict__ Al,
    const _Float16* __restrict__ Wh, const _Float16* __restrict__ Wl,
    const float* __restrict__ bias, const float* __restrict__ resid,
    float* __restrict__ Cf, _Float16* __restrict__ Ch, _Float16* __restrict__ Cl,
    _Float16* __restrict__ vtb, int N)
{
  const int n0 = blockIdx.x * (NT * 16);
  const int m0 = blockIdx.y * 64;
  const int t = threadIdx.x, w = t >> 6, l = t & 63;
  const int ml = l & 15, g = l >> 4;
  const int mrow = m0 + w * 16 + ml;

  const _Float16* aph = Ah + (size_t)mrow * KK + g * 8;
  const _Float16* apl = Al + (size_t)mrow * KK + g * 8;
  const _Float16* whp[NT];
  const _Float16* wlp[NT];
  #pragma unroll
  for (int nt = 0; nt < NT; nt++) {
    int nrow = n0 + nt * 16 + ml;
    whp[nt] = Wh + (size_t)nrow * KK + g * 8;
    wlp[nt] = Wl + (size_t)nrow * KK + g * 8;
  }

  fx4 acc[NT];
  #pragma unroll
  for (int nt = 0; nt < NT; nt++) acc[nt] = (fx4){0.f, 0.f, 0.f, 0.f};

  #pragma unroll 4
  for (int k0 = 0; k0 < KK; k0 += 32) {
    h8 ah = *(const h8*)(aph + k0);
    h8 al = *(const h8*)(apl + k0);
    #pragma unroll
    for (int nt = 0; nt < NT; nt++) {
      h8 wh = *(const h8*)(whp[nt] + k0);
      h8 wl = *(const h8*)(wlp[nt] + k0);
      acc[nt] = __builtin_amdgcn_mfma_f32_16x16x32_f16(al, wh, acc[nt], 0, 0, 0);
      acc[nt] = __builtin_amdgcn_mfma_f32_16x16x32_f16(ah, wl, acc[nt], 0, 0, 0);
      acc[nt] = __builtin_amdgcn_mfma_f32_16x16x32_f16(ah, wh, acc[nt], 0, 0, 0);
    }
  }

  #pragma unroll
  for (int nt = 0; nt < NT; nt++) {
    int n = n0 + nt * 16 + ml;
    float bv = bias[n];
    #pragma unroll
    for (int i = 0; i < 4; i++) {
      int m = m0 + w * 16 + 4 * g + i;
      float vv = acc[nt][i] + bv;
      if (ACT == 1) vv = 0.5f * vv * (1.0f + erff(vv * 0.70710678118654752f));
      if (RES)      vv += resid[(size_t)m * N + n];
      if (OM == 0) {
        Cf[(size_t)m * N + n] = vv;
      } else if (OM == 1) {
        _Float16 hi = (_Float16)vv;
        Ch[(size_t)m * N + n] = hi;
        Cl[(size_t)m * N + n] = (_Float16)(vv - (float)hi);
      } else {   // OM == 2: qkv
        if (n < 512) Ch[(size_t)m * QKVLD + n] = (_Float16)vv;
        else vtb[((size_t)(m >> 11) * HD + (n - 512)) * NN + (m & (NN - 1))] = (_Float16)vv;
      }
    }
  }
}

// ---------------- MFMA flash attention: pure fp16, split-KV, log2-domain softmax ----------
// qkv16: [4096][768] fp16 (Q pre-scaled by log2e/sqrt32); vtb: [b][dim(256)][kv(2048)] fp16.
__global__ __launch_bounds__(256) void attn_mfma_kernel(
    const _Float16* __restrict__ qkv16, const _Float16* __restrict__ vtb,
    const float* __restrict__ adj,
    float* __restrict__ Opart, float* __restrict__ Mpart, float* __restrict__ Spart)
{
  __shared__ _Float16 Ksh[64][40];   // [kv][dim]
  __shared__ _Float16 Vth[32][72];   // [dim][kv]

  const int z = blockIdx.z;
  const int b = z >> 1, half = z & 1;
  const int h = blockIdx.y;
  const int q0 = blockIdx.x * 64;
  const int t = threadIdx.x;
  const int w = t >> 6, l = t & 63;
  const int m = l & 15, g = l >> 4;
  const int kvbase = half * (NN / 2);

  const int qrow = q0 + w * 16 + m;
  h8 qh = *(const h8*)(qkv16 + ((size_t)(b * NN + qrow)) * QKVLD + h * DH + g * 8);

  fx4 ot0 = {0.f, 0.f, 0.f, 0.f};
  fx4 ot1 = {0.f, 0.f, 0.f, 0.f};
  float M = -3.0e38f, S = 0.0f;

  const float* adjrow = adj + ((size_t)(b * NN + qrow)) * NN + kvbase;

  // staging roles (pure fp16 copies)
  const int krow = t >> 2, kd0 = (t & 3) * 8;   // K: 64 rows x 32 dims
  const int vdim = t >> 3, vkc = (t & 7) * 8;   // V^T: 32 dims x 64 kv
  const _Float16* kbase = qkv16 + ((size_t)(b * NN + kvbase + krow)) * QKVLD + 256 + h * DH + kd0;
  const _Float16* vbase = vtb + ((size_t)(b * HD + h * DH + vdim)) * NN + kvbase + vkc;
  h8 kreg = *(const h8*)kbase;
  h8 vreg = *(const h8*)vbase;
  float4 adjreg[4];
  #pragma unroll
  for (int p = 0; p < 4; p++) adjreg[p] = *(const float4*)(adjrow + p * 16 + g * 4);

  for (int kt = 0; kt < NN / 2; kt += 64) {
    __syncthreads();
    *(h8*)&Ksh[krow][kd0] = kreg;
    *(h8*)&Vth[vdim][vkc] = vreg;
    __syncthreads();

    const bool more = (kt + 64 < NN / 2);
    float4 a4[4];
    #pragma unroll
    for (int p = 0; p < 4; p++) a4[p] = adjreg[p];
    if (more) {
      kreg = *(const h8*)(kbase + (size_t)(kt + 64) * QKVLD);
      vreg = *(const h8*)(vbase + kt + 64);
      #pragma unroll
      for (int p = 0; p < 4; p++) adjreg[p] = *(const float4*)(adjrow + kt + 64 + p * 16 + g * 4);
    }

    // ---- QK^T for the whole 64-kv tile (log2-domain logits) ----
    h8 kh0 = *(const h8*)&Ksh[     m][g * 8];
    h8 kh1 = *(const h8*)&Ksh[16 + m][g * 8];
    h8 kh2 = *(const h8*)&Ksh[32 + m][g * 8];
    h8 kh3 = *(const h8*)&Ksh[48 + m][g * 8];
    fx4 z4 = {0.f, 0.f, 0.f, 0.f};
    fx4 st[4];
    st[0] = __builtin_amdgcn_mfma_f32_16x16x32_f16(kh0, qh, z4, 0, 0, 0);
    st[1] = __builtin_amdgcn_mfma_f32_16x16x32_f16(kh1, qh, z4, 0, 0, 0);
    st[2] = __builtin_amdgcn_mfma_f32_16x16x32_f16(kh2, qh, z4, 0, 0, 0);
    st[3] = __builtin_amdgcn_mfma_f32_16x16x32_f16(kh3, qh, z4, 0, 0, 0);

    float lv[16];
    float tmax = -3.0e38f;
    #pragma unroll
    for (int p = 0; p < 4; p++) {
      const float* ap = (const float*)&a4[p];
      #pragma unroll
      for (int i = 0; i < 4; i++) {
        float lvv = st[p][i] + (2.0f * LOG2E) * ap[i] - LOG2E;
        lv[p * 4 + i] = lvv;
        tmax = fmaxf(tmax, lvv);
      }
    }
    tmax = fmaxf(tmax, __shfl_xor(tmax, 16));
    tmax = fmaxf(tmax, __shfl_xor(tmax, 32));
    // defer-max: only rescale when some row's tile-max exceeds M+8 (P <= 2^8)
    if (!__all(tmax <= M + 8.0f)) {
      float mnew = fmaxf(M, tmax);
      float resc = exp2f(M - mnew);
      S *= resc; ot0 *= resc; ot1 *= resc;
      M = mnew;
    }
    float pv[16];
    #pragma unroll
    for (int p = 0; p < 4; p++) {
      const float* ap = (const float*)&a4[p];
      #pragma unroll
      for (int i = 0; i < 4; i++) {
        float e = exp2f(lv[p * 4 + i] - M);
        float pp = (0.25f + 0.75f * ap[i]) * e;
        pv[p * 4 + i] = pp;
        S += pp;
      }
    }
    h8 ph0, ph1;
    #pragma unroll
    for (int i = 0; i < 4; i++) {
      ph0[i]     = (_Float16)pv[i];        // kv  4g+i
      ph0[4 + i] = (_Float16)pv[4 + i];    // kv 16+4g+i
      ph1[i]     = (_Float16)pv[8 + i];    // kv 32+4g+i
      ph1[4 + i] = (_Float16)pv[12 + i];   // kv 48+4g+i
    }

    // ---- PV: O^T += V^T_frag @ P^T_frag ----
    h4 t00 = *(const h4*)&Vth[m][      g * 4];
    h4 t01 = *(const h4*)&Vth[m][16 + g * 4];
    h4 t02 = *(const h4*)&Vth[m][32 + g * 4];
    h4 t03 = *(const h4*)&Vth[m][48 + g * 4];
    h4 t10 = *(const h4*)&Vth[16 + m][      g * 4];
    h4 t11 = *(const h4*)&Vth[16 + m][16 + g * 4];
    h4 t12 = *(const h4*)&Vth[16 + m][32 + g * 4];
    h4 t13 = *(const h4*)&Vth[16 + m][48 + g * 4];
    h8 v00, v01, v10, v11;
    #pragma unroll
    for (int j = 0; j < 4; j++) {
      v00[j] = t00[j]; v00[4 + j] = t01[j];
      v01[j] = t02[j]; v01[4 + j] = t03[j];
      v10[j] = t10[j]; v10[4 + j] = t11[j];
      v11[j] = t12[j]; v11[4 + j] = t13[j];
    }
    ot0 = __builtin_amdgcn_mfma_f32_16x16x32_f16(v00, ph0, ot0, 0, 0, 0);
    ot0 = __builtin_amdgcn_mfma_f32_16x16x32_f16(v01, ph1, ot0, 0, 0, 0);
    ot1 = __builtin_amdgcn_mfma_f32_16x16x32_f16(v10, ph0, ot1, 0, 0, 0);
    ot1 = __builtin_amdgcn_mfma_f32_16x16x32_f16(v11, ph1, ot1, 0, 0, 0);
  }

  // denominator: per-lane partial (16 of 64 kv per tile) -> reduce across lane^16, lane^32
  S += __shfl_xor(S, 16);
  S += __shfl_xor(S, 32);

  size_t prow = ((size_t)(z * NH + h)) * NN + qrow;
  float* po = Opart + prow * 32;
  *(float4*)(po + 4 * g)      = make_float4(ot0[0], ot0[1], ot0[2], ot0[3]);
  *(float4*)(po + 16 + 4 * g) = make_float4(ot1[0], ot1[1], ot1[2], ot1[3]);
  if (g == 0) { Mpart[prow] = M; Spart[prow] = S; }
}

// ---------------- combine the two KV halves -> fp16 hi/lo att ----------------
__global__ __launch_bounds__(256) void attn_combine_kernel(
    const float* __restrict__ Opart, const float* __restrict__ Mpart,
    const float* __restrict__ Spart, _Float16* __restrict__ atth,
    _Float16* __restrict__ attl)
{
  int idx = blockIdx.x * 256 + threadIdx.x;   // BB*NH*NN*8 total
  int dg  = idx & 7;
  int rowid = idx >> 3;                        // (b*NH+h)*NN + qrow
  int qrow = rowid & (NN - 1);
  int bh = rowid >> 11;
  int b = bh >> 3, h = bh & 7;
  size_t p0 = ((size_t)((b * 2 + 0) * NH + h)) * NN + qrow;
  size_t p1 = ((size_t)((b * 2 + 1) * NH + h)) * NN + qrow;
  float m0 = Mpart[p0], m1 = Mpart[p1];
  float s0 = Spart[p0], s1 = Spart[p1];
  float mm = fmaxf(m0, m1);
  float e0 = exp2f(m0 - mm), e1 = exp2f(m1 - mm);
  float is = 1.0f / (s0 * e0 + s1 * e1);
  float4 o0 = *(const float4*)(Opart + p0 * 32 + dg * 4);
  float4 o1 = *(const float4*)(Opart + p1 * 32 + dg * 4);
  float ov[4];
  ov[0] = (o0.x * e0 + o1.x * e1) * is;
  ov[1] = (o0.y * e0 + o1.y * e1) * is;
  ov[2] = (o0.z * e0 + o1.z * e1) * is;
  ov[3] = (o0.w * e0 + o1.w * e1) * is;
  h4 hh, hl;
  #pragma unroll
  for (int j = 0; j < 4; j++) {
    _Float16 hi = (_Float16)ov[j];
    hh[j] = hi; hl[j] = (_Float16)(ov[j] - (float)hi);
  }
  size_t off = ((size_t)(b * NN + qrow)) * HD + h * DH + dg * 4;
  *(h4*)(atth + off) = hh;
  *(h4*)(attl + off) = hl;
}

extern "C" void kernel_launch(void* const* d_in, const int* in_sizes, int n_in,
                              void* d_out, int out_size, void* d_ws, size_t ws_size,
                              hipStream_t stream)
{
  const float* hidden    = (const float*)d_in[0];
  const float* adjacency = (const float*)d_in[1];
  const float* wq  = (const float*)d_in[3];
  const float* bq  = (const float*)d_in[4];
  const float* wk  = (const float*)d_in[5];
  const float* bk  = (const float*)d_in[6];
  const float* wv  = (const float*)d_in[7];
  const float* bv  = (const float*)d_in[8];
  const float* wo  = (const float*)d_in[9];
  const float* bo  = (const float*)d_in[10];
  const float* g1  = (const float*)d_in[11];
  const float* b1  = (const float*)d_in[12];
  const float* g2  = (const float*)d_in[13];
  const float* b2  = (const float*)d_in[14];
  const float* wf1 = (const float*)d_in[15];
  const float* bf1 = (const float*)d_in[16];
  const float* wf2 = (const float*)d_in[17];
  const float* bf2 = (const float*)d_in[18];
  float* out = (float*)d_out;

  char* base = (char*)d_ws;
  const size_t MB = 1024 * 1024;
  _Float16* norm1h = (_Float16*)(base);          // [0,2) MB
  _Float16* norm1l = (_Float16*)(base + 2*MB);   // [2,4)
  _Float16* qkv16  = (_Float16*)(base + 4*MB);   // [4,10): [4096][768]
  _Float16* vtb    = (_Float16*)(base + 10*MB);  // [10,12): [2][256][2048]
  _Float16* atth   = (_Float16*)(base + 12*MB);  // [12,14)
  _Float16* attl   = (_Float16*)(base + 14*MB);  // [14,16)
  float*    hid2   = (float*)(base + 16*MB);     // [16,20) f32
  _Float16* ffah   = (_Float16*)(base + 20*MB);  // [20,28): [4096][1024]
  _Float16* ffal   = (_Float16*)(base + 28*MB);  // [28,36)
  // attn partials overlay the ffa region (dead until FF1):
  float* Opart = (float*)(base + 20*MB);         // 8 MB
  float* Mpart = (float*)(base + 28*MB);         // 256 KB
  float* Spart = (float*)(base + 29*MB);         // 256 KB
  _Float16* wtb = (_Float16*)(base + 36*MB);
  _Float16* WtQKVh = wtb; wtb += 768 * 256;
  _Float16* WtQKVl = wtb; wtb += 768 * 256;
  _Float16* WtOh   = wtb; wtb += 256 * 256;
  _Float16* WtOl   = wtb; wtb += 256 * 256;
  _Float16* WtF1h  = wtb; wtb += 1024 * 256;
  _Float16* WtF1l  = wtb; wtb += 1024 * 256;
  _Float16* WtF2h  = wtb; wtb += 256 * 1024;
  _Float16* WtF2l  = wtb; wtb += 256 * 1024;
  float* biasqkv = (float*)(base + 40*MB);

  // wq/bq pre-scaled by log2(e)/sqrt(32): QK logits come out in log2 domain.
  transpose_w_kernel<<<dim3(8, 8),  256, 0, stream>>>(wq,  WtQKVh, WtQKVl, 256,    0,  256, SQ_LOG2);
  transpose_w_kernel<<<dim3(8, 8),  256, 0, stream>>>(wk,  WtQKVh, WtQKVl, 256,  256,  256, 1.0f);
  transpose_w_kernel<<<dim3(8, 8),  256, 0, stream>>>(wv,  WtQKVh, WtQKVl, 256,  512,  256, 1.0f);
  transpose_w_kernel<<<dim3(8, 8),  256, 0, stream>>>(wo,  WtOh,   WtOl,   256,    0,  256, 1.0f);
  transpose_w_kernel<<<dim3(32, 8), 256, 0, stream>>>(wf1, WtF1h,  WtF1l,  1024,   0,  256, 1.0f);
  transpose_w_kernel<<<dim3(8, 32), 256, 0, stream>>>(wf2, WtF2h,  WtF2l,  256,    0, 1024, 1.0f);
  concat3_kernel<<<3, 256, 0, stream>>>(bq, bk, bv, biasqkv);

  ln_kernel<<<NTOK / 4, 256, 0, stream>>>(hidden, g1, b1, norm1h, norm1l);

  // fused QKV -> fp16 qkv (Q,K) + transposed fp16 V
  gemm_mfma_kernel<256, 4, 0, 0, 2><<<dim3(12, 64), 256, 0, stream>>>(
      norm1h, norm1l, WtQKVh, WtQKVl, biasqkv, nullptr,
      nullptr, qkv16, nullptr, vtb, QKVLD);

  attn_mfma_kernel<<<dim3(NN / 64, NH, BB * 2), 256, 0, stream>>>(
      qkv16, vtb, adjacency, Opart, Mpart, Spart);
  attn_combine_kernel<<<(BB * NH * NN * 8) / 256, 256, 0, stream>>>(
      Opart, Mpart, Spart, atth, attl);

  gemm_mfma_kernel<256, 2, 0, 1, 0><<<dim3(8, 64), 256, 0, stream>>>(
      atth, attl, WtOh, WtOl, bo, hidden,
      hid2, nullptr, nullptr, nullptr, 256);

  ln_kernel<<<NTOK / 4, 256, 0, stream>>>(hid2, g2, b2, norm1h, norm1l);

  gemm_mfma_kernel<256, 4, 1, 0, 1><<<dim3(16, 64), 256, 0, stream>>>(
      norm1h, norm1l, WtF1h, WtF1l, bf1, nullptr,
      nullptr, ffah, ffal, nullptr, 1024);

  gemm_mfma_kernel<1024, 2, 0, 1, 0><<<dim3(8, 64), 256, 0, stream>>>(
      ffah, ffal, WtF2h, WtF2l, bf2, hid2,
      out, nullptr, nullptr, nullptr, 256);
}

// Round 9
// 189.345 us; speedup vs baseline: 2.5284x; 1.0673x over previous
//
#include <hip/hip_runtime.h>
#include <math.h>

#define BB 2
#define NN 2048
#define HD 256
#define NH 8
#define DH 32
#define NTOK (BB*NN)   // 4096
#define QKVLD 768      // fused qkv row stride (fp16)
#define NSPLIT 4       // split-KV ways

typedef _Float16 h8 __attribute__((ext_vector_type(8)));
typedef _Float16 h4 __attribute__((ext_vector_type(4)));
typedef float fx4 __attribute__((ext_vector_type(4)));

#define LOG2E 1.4426950408889634f
#define SQ_LOG2 0.25503486f   // log2(e)/sqrt(32), folded into wq/bq

// ---------------- LayerNorm: f32 in -> fp16 hi/lo out ----------------
__global__ __launch_bounds__(256) void ln_kernel(const float* __restrict__ x,
    const float* __restrict__ g, const float* __restrict__ bta,
    _Float16* __restrict__ yh, _Float16* __restrict__ yl)
{
  int row  = blockIdx.x * 4 + (threadIdx.x >> 6);
  int lane = threadIdx.x & 63;
  const float* xr = x + (size_t)row * HD + lane * 4;
  float4 v = *(const float4*)xr;
  float s = v.x + v.y + v.z + v.w;
  #pragma unroll
  for (int off = 32; off > 0; off >>= 1) s += __shfl_xor(s, off);
  float mu = s * (1.0f / HD);
  float dx0 = v.x - mu, dx1 = v.y - mu, dx2 = v.z - mu, dx3 = v.w - mu;
  float ss = dx0*dx0 + dx1*dx1 + dx2*dx2 + dx3*dx3;
  #pragma unroll
  for (int off = 32; off > 0; off >>= 1) ss += __shfl_xor(ss, off);
  float rinv = rsqrtf(ss * (1.0f / HD) + 1e-5f);
  float4 gv = *(const float4*)(g   + lane * 4);
  float4 bv = *(const float4*)(bta + lane * 4);
  float o[4];
  o[0] = dx0 * rinv * gv.x + bv.x;
  o[1] = dx1 * rinv * gv.y + bv.y;
  o[2] = dx2 * rinv * gv.z + bv.z;
  o[3] = dx3 * rinv * gv.w + bv.w;
  h4 hh, hl;
  #pragma unroll
  for (int j = 0; j < 4; j++) {
    _Float16 hi = (_Float16)o[j];
    hh[j] = hi; hl[j] = (_Float16)(o[j] - (float)hi);
  }
  *(h4*)(yh + (size_t)row * HD + lane * 4) = hh;
  *(h4*)(yl + (size_t)row * HD + lane * 4) = hl;
}

// ---------------- fused prep: all 6 weight transposes + bias concat, one launch -------
// transpose task: W[K][N] f32 -> Wh/Wl [N][K] fp16 (scaled)
__device__ __forceinline__ void do_transpose(const float* __restrict__ W,
    _Float16* __restrict__ Wh, _Float16* __restrict__ Wl,
    int Nw, int rowoff, int ldout, float scale, int bx, int by,
    float (*tile)[33])
{
  int k0 = by * 32, n0 = bx * 32;
  int c = threadIdx.x & 31, r = threadIdx.x >> 5;   // r 0..7
  #pragma unroll
  for (int i = 0; i < 4; i++)
    tile[r + i * 8][c] = W[(size_t)(k0 + r + i * 8) * Nw + n0 + c];
  __syncthreads();
  #pragma unroll
  for (int i = 0; i < 4; i++) {
    int n = r + i * 8;
    float x = tile[c][n] * scale;
    _Float16 hi = (_Float16)x;
    Wh[(size_t)(rowoff + n0 + n) * ldout + k0 + c] = hi;
    Wl[(size_t)(rowoff + n0 + n) * ldout + k0 + c] = (_Float16)(x - (float)hi);
  }
}

__global__ __launch_bounds__(256) void prep_kernel(
    const float* wq, const float* wk, const float* wv, const float* wo,
    const float* wf1, const float* wf2,
    const float* bq, const float* bk, const float* bv,
    _Float16* WtQKVh, _Float16* WtQKVl, _Float16* WtOh, _Float16* WtOl,
    _Float16* WtF1h, _Float16* WtF1l, _Float16* WtF2h, _Float16* WtF2l,
    float* biasqkv)
{
  __shared__ float tile[32][33];
  int bid = blockIdx.x;
  if (bid < 64)        do_transpose(wq,  WtQKVh, WtQKVl,  256,   0,  256, SQ_LOG2, bid & 7, bid >> 3, tile);
  else if (bid < 128)  do_transpose(wk,  WtQKVh, WtQKVl,  256, 256,  256, 1.0f, (bid-64) & 7, (bid-64) >> 3, tile);
  else if (bid < 192)  do_transpose(wv,  WtQKVh, WtQKVl,  256, 512,  256, 1.0f, (bid-128) & 7, (bid-128) >> 3, tile);
  else if (bid < 256)  do_transpose(wo,  WtOh,   WtOl,    256,   0,  256, 1.0f, (bid-192) & 7, (bid-192) >> 3, tile);
  else if (bid < 512)  do_transpose(wf1, WtF1h,  WtF1l,  1024,   0,  256, 1.0f, (bid-256) & 31, (bid-256) >> 5, tile);
  else if (bid < 768)  do_transpose(wf2, WtF2h,  WtF2l,   256,   0, 1024, 1.0f, (bid-512) & 7, (bid-512) >> 3, tile);
  else {
    #pragma unroll
    for (int j = 0; j < 3; j++) {
      int t = j * 256 + threadIdx.x;
      biasqkv[t] = (t < 256) ? bq[t] * SQ_LOG2 : (t < 512) ? bk[t - 256] : bv[t - 512];
    }
  }
}

// ---------------- MFMA GEMM, direct-fragment, fp16 hi/lo A and W ----------------
// OM: 0 = f32 C (+resid); 1 = fp16 hi/lo pair out; 2 = qkv mode (fp16; V transposed+pair-interleaved)
template<int KK, int NT, int ACT, int RES, int OM>
__global__ __launch_bounds__(256) void gemm_mfma_kernel(
    const _Float16* __restrict__ Ah, const _Float16* __restrict__ Al,
    const _Float16* __restrict__ Wh, const _Float16* __restrict__ Wl,
    const float* __restrict__ bias, const float* __restrict__ resid,
    float* __restrict__ Cf, _Float16* __restrict__ Ch, _Float16* __restrict__ Cl,
    _Float16* __restrict__ vtb, int N)
{
  const int n0 = blockIdx.x * (NT * 16);
  const int m0 = blockIdx.y * 64;
  const int t = threadIdx.x, w = t >> 6, l = t & 63;
  const int ml = l & 15, g = l >> 4;
  const int mrow = m0 + w * 16 + ml;

  const _Float16* aph = Ah + (size_t)mrow * KK + g * 8;
  const _Float16* apl = Al + (size_t)mrow * KK + g * 8;
  const _Float16* whp[NT];
  const _Float16* wlp[NT];
  #pragma unroll
  for (int nt = 0; nt < NT; nt++) {
    int nrow = n0 + nt * 16 + ml;
    whp[nt] = Wh + (size_t)nrow * KK + g * 8;
    wlp[nt] = Wl + (size_t)nrow * KK + g * 8;
  }

  fx4 acc[NT];
  #pragma unroll
  for (int nt = 0; nt < NT; nt++) acc[nt] = (fx4){0.f, 0.f, 0.f, 0.f};

  #pragma unroll 4
  for (int k0 = 0; k0 < KK; k0 += 32) {
    h8 ah = *(const h8*)(aph + k0);
    h8 al = *(const h8*)(apl + k0);
    #pragma unroll
    for (int nt = 0; nt < NT; nt++) {
      h8 wh = *(const h8*)(whp[nt] + k0);
      h8 wl = *(const h8*)(wlp[nt] + k0);
      acc[nt] = __builtin_amdgcn_mfma_f32_16x16x32_f16(al, wh, acc[nt], 0, 0, 0);
      acc[nt] = __builtin_amdgcn_mfma_f32_16x16x32_f16(ah, wl, acc[nt], 0, 0, 0);
      acc[nt] = __builtin_amdgcn_mfma_f32_16x16x32_f16(ah, wh, acc[nt], 0, 0, 0);
    }
  }

  #pragma unroll
  for (int nt = 0; nt < NT; nt++) {
    int n = n0 + nt * 16 + ml;
    float bv = bias[n];
    #pragma unroll
    for (int i = 0; i < 4; i++) {
      int m = m0 + w * 16 + 4 * g + i;
      float vv = acc[nt][i] + bv;
      if (ACT == 1) vv = 0.5f * vv * (1.0f + erff(vv * 0.70710678118654752f));
      if (RES)      vv += resid[(size_t)m * N + n];
      if (OM == 0) {
        Cf[(size_t)m * N + n] = vv;
      } else if (OM == 1) {
        _Float16 hi = (_Float16)vv;
        Ch[(size_t)m * N + n] = hi;
        Cl[(size_t)m * N + n] = (_Float16)(vv - (float)hi);
      } else {   // OM == 2: qkv; V transposed with pair-interleaved kv index
        if (n < 512) Ch[(size_t)m * QKVLD + n] = (_Float16)vv;
        else {
          int dim = n - 512, kv = m & (NN - 1), bb = m >> 11;
          int kvp = (kv & ~31) | ((kv & 15) << 1) | ((kv >> 4) & 1);
          vtb[((size_t)(bb * HD + dim)) * NN + kvp] = (_Float16)vv;
        }
      }
    }
  }
}

// ---------------- MFMA flash attention: fp16, 4-way split-KV, log2 softmax ----------
// qkv16: [4096][768] fp16 (Q pre-scaled); vtb: [b][dim][kv'] fp16, kv' pair-interleaved:
// kv' = (kv&~31) | ((kv&15)<<1) | ((kv>>4)&1). A V-fragment is then ONE contiguous h8;
// the matching k-slot map (slot j <-> kv s*32 + (j&1)*16 + 4g + (j>>1)) is applied to P.
__global__ __launch_bounds__(256) void attn_mfma_kernel(
    const _Float16* __restrict__ qkv16, const _Float16* __restrict__ vtb,
    const float* __restrict__ adj,
    float* __restrict__ Opart, float* __restrict__ Mpart, float* __restrict__ Spart)
{
  __shared__ _Float16 Ksh[64][40];   // [kv][dim]
  __shared__ _Float16 Vp[32][72];    // [dim][kv' within tile]

  const int z = blockIdx.z;                  // b*NSPLIT + quarter
  const int b = z >> 2, quarter = z & 3;
  const int h = blockIdx.y;
  const int q0 = blockIdx.x * 64;
  const int t = threadIdx.x;
  const int w = t >> 6, l = t & 63;
  const int m = l & 15, g = l >> 4;
  const int kvbase = quarter * (NN / NSPLIT);   // 512 kv per block

  const int qrow = q0 + w * 16 + m;
  h8 qh = *(const h8*)(qkv16 + ((size_t)(b * NN + qrow)) * QKVLD + h * DH + g * 8);

  fx4 ot0 = {0.f, 0.f, 0.f, 0.f};
  fx4 ot1 = {0.f, 0.f, 0.f, 0.f};
  float M = -3.0e38f, S = 0.0f;

  const float* adjrow = adj + ((size_t)(b * NN + qrow)) * NN + kvbase;

  // staging roles (pure fp16 16B copies)
  const int krow = t >> 2, kd0 = (t & 3) * 8;   // K: 64 rows x 32 dims
  const int vdim = t >> 3, vkc = (t & 7) * 8;   // V': 32 dims x 64 kv'
  const _Float16* kbase = qkv16 + ((size_t)(b * NN + kvbase + krow)) * QKVLD + 256 + h * DH + kd0;
  const _Float16* vbase = vtb + ((size_t)(b * HD + h * DH + vdim)) * NN + kvbase + vkc;
  h8 kreg = *(const h8*)kbase;
  h8 vreg = *(const h8*)vbase;
  float4 adjreg[4];
  #pragma unroll
  for (int p = 0; p < 4; p++) adjreg[p] = *(const float4*)(adjrow + p * 16 + g * 4);

  for (int kt = 0; kt < NN / NSPLIT; kt += 64) {
    __syncthreads();
    *(h8*)&Ksh[krow][kd0] = kreg;
    *(h8*)&Vp[vdim][vkc]  = vreg;
    __syncthreads();

    float4 a4[4];
    #pragma unroll
    for (int p = 0; p < 4; p++) a4[p] = adjreg[p];
    if (kt + 64 < NN / NSPLIT) {
      kreg = *(const h8*)(kbase + (size_t)(kt + 64) * QKVLD);
      vreg = *(const h8*)(vbase + kt + 64);
      #pragma unroll
      for (int p = 0; p < 4; p++) adjreg[p] = *(const float4*)(adjrow + kt + 64 + p * 16 + g * 4);
    }

    // ---- QK^T for the 64-kv tile (log2-domain logits) ----
    h8 kh0 = *(const h8*)&Ksh[     m][g * 8];
    h8 kh1 = *(const h8*)&Ksh[16 + m][g * 8];
    h8 kh2 = *(const h8*)&Ksh[32 + m][g * 8];
    h8 kh3 = *(const h8*)&Ksh[48 + m][g * 8];
    fx4 z4 = {0.f, 0.f, 0.f, 0.f};
    fx4 st[4];
    st[0] = __builtin_amdgcn_mfma_f32_16x16x32_f16(kh0, qh, z4, 0, 0, 0);
    st[1] = __builtin_amdgcn_mfma_f32_16x16x32_f16(kh1, qh, z4, 0, 0, 0);
    st[2] = __builtin_amdgcn_mfma_f32_16x16x32_f16(kh2, qh, z4, 0, 0, 0);
    st[3] = __builtin_amdgcn_mfma_f32_16x16x32_f16(kh3, qh, z4, 0, 0, 0);

    float lv[16];
    float tmax = -3.0e38f;
    #pragma unroll
    for (int p = 0; p < 4; p++) {
      const float* ap = (const float*)&a4[p];
      #pragma unroll
      for (int i = 0; i < 4; i++) {
        float lvv = st[p][i] + (2.0f * LOG2E) * ap[i] - LOG2E;
        lv[p * 4 + i] = lvv;
        tmax = fmaxf(tmax, lvv);
      }
    }
    tmax = fmaxf(tmax, __shfl_xor(tmax, 16));
    tmax = fmaxf(tmax, __shfl_xor(tmax, 32));
    // defer-max: rescale only when some row's tile-max exceeds M+8
    if (!__all(tmax <= M + 8.0f)) {
      float mnew = fmaxf(M, tmax);
      float resc = __builtin_amdgcn_exp2f(M - mnew);
      S *= resc; ot0 *= resc; ot1 *= resc;
      M = mnew;
    }
    float pv[16];
    #pragma unroll
    for (int p = 0; p < 4; p++) {
      const float* ap = (const float*)&a4[p];
      #pragma unroll
      for (int i = 0; i < 4; i++) {
        float e = __builtin_amdgcn_exp2f(lv[p * 4 + i] - M);
        float pp = (0.25f + 0.75f * ap[i]) * e;
        pv[p * 4 + i] = pp;
        S += pp;
      }
    }
    // pack P in pair-interleaved k-slot order: slot j <-> kv s*32 + (j&1)*16 + 4g + (j>>1)
    h8 ph0, ph1;
    #pragma unroll
    for (int q2 = 0; q2 < 4; q2++) {
      ph0[2*q2]     = (_Float16)pv[q2];        // s=0: kv 4g+q2
      ph0[2*q2 + 1] = (_Float16)pv[4 + q2];    // s=0: kv 16+4g+q2
      ph1[2*q2]     = (_Float16)pv[8 + q2];    // s=1: kv 32+4g+q2
      ph1[2*q2 + 1] = (_Float16)pv[12 + q2];   // s=1: kv 48+4g+q2
    }

    // ---- PV: each V fragment is one contiguous h8 (pair-interleaved layout) ----
    h8 v00 = *(const h8*)&Vp[m][g * 8];
    h8 v01 = *(const h8*)&Vp[m][32 + g * 8];
    h8 v10 = *(const h8*)&Vp[16 + m][g * 8];
    h8 v11 = *(const h8*)&Vp[16 + m][32 + g * 8];
    ot0 = __builtin_amdgcn_mfma_f32_16x16x32_f16(v00, ph0, ot0, 0, 0, 0);
    ot0 = __builtin_amdgcn_mfma_f32_16x16x32_f16(v01, ph1, ot0, 0, 0, 0);
    ot1 = __builtin_amdgcn_mfma_f32_16x16x32_f16(v10, ph0, ot1, 0, 0, 0);
    ot1 = __builtin_amdgcn_mfma_f32_16x16x32_f16(v11, ph1, ot1, 0, 0, 0);
  }

  // denominator: per-lane partial -> reduce across lane^16, lane^32
  S += __shfl_xor(S, 16);
  S += __shfl_xor(S, 32);

  size_t prow = ((size_t)(z * NH + h)) * NN + qrow;
  float* po = Opart + prow * 32;
  *(float4*)(po + 4 * g)      = make_float4(ot0[0], ot0[1], ot0[2], ot0[3]);
  *(float4*)(po + 16 + 4 * g) = make_float4(ot1[0], ot1[1], ot1[2], ot1[3]);
  if (g == 0) { Mpart[prow] = M; Spart[prow] = S; }
}

// ---------------- combine the NSPLIT KV quarters -> fp16 hi/lo att ----------------
__global__ __launch_bounds__(256) void attn_combine_kernel(
    const float* __restrict__ Opart, const float* __restrict__ Mpart,
    const float* __restrict__ Spart, _Float16* __restrict__ atth,
    _Float16* __restrict__ attl)
{
  int idx = blockIdx.x * 256 + threadIdx.x;   // BB*NH*NN*8 total
  int dg  = idx & 7;
  int rowid = idx >> 3;                        // (b*NH+h)*NN + qrow
  int qrow = rowid & (NN - 1);
  int bh = rowid >> 11;
  int b = bh >> 3, h = bh & 7;
  size_t p[NSPLIT];
  float mz[NSPLIT], sz[NSPLIT];
  float mm = -3.0e38f;
  #pragma unroll
  for (int zq = 0; zq < NSPLIT; zq++) {
    p[zq] = ((size_t)((b * NSPLIT + zq) * NH + h)) * NN + qrow;
    mz[zq] = Mpart[p[zq]];
    sz[zq] = Spart[p[zq]];
    mm = fmaxf(mm, mz[zq]);
  }
  float den = 0.f;
  float ez[NSPLIT];
  #pragma unroll
  for (int zq = 0; zq < NSPLIT; zq++) {
    ez[zq] = __builtin_amdgcn_exp2f(mz[zq] - mm);
    den += sz[zq] * ez[zq];
  }
  float is = 1.0f / den;
  float ov[4] = {0.f, 0.f, 0.f, 0.f};
  #pragma unroll
  for (int zq = 0; zq < NSPLIT; zq++) {
    float4 o = *(const float4*)(Opart + p[zq] * 32 + dg * 4);
    ov[0] += o.x * ez[zq]; ov[1] += o.y * ez[zq];
    ov[2] += o.z * ez[zq]; ov[3] += o.w * ez[zq];
  }
  h4 hh, hl;
  #pragma unroll
  for (int j = 0; j < 4; j++) {
    float x = ov[j] * is;
    _Float16 hi = (_Float16)x;
    hh[j] = hi; hl[j] = (_Float16)(x - (float)hi);
  }
  size_t off = ((size_t)(b * NN + qrow)) * HD + h * DH + dg * 4;
  *(h4*)(atth + off) = hh;
  *(h4*)(attl + off) = hl;
}

extern "C" void kernel_launch(void* const* d_in, const int* in_sizes, int n_in,
                              void* d_out, int out_size, void* d_ws, size_t ws_size,
                              hipStream_t stream)
{
  const float* hidden    = (const float*)d_in[0];
  const float* adjacency = (const float*)d_in[1];
  const float* wq  = (const float*)d_in[3];
  const float* bq  = (const float*)d_in[4];
  const float* wk  = (const float*)d_in[5];
  const float* bk  = (const float*)d_in[6];
  const float* wv  = (const float*)d_in[7];
  const float* bv  = (const float*)d_in[8];
  const float* wo  = (const float*)d_in[9];
  const float* bo  = (const float*)d_in[10];
  const float* g1  = (const float*)d_in[11];
  const float* b1  = (const float*)d_in[12];
  const float* g2  = (const float*)d_in[13];
  const float* b2  = (const float*)d_in[14];
  const float* wf1 = (const float*)d_in[15];
  const float* bf1 = (const float*)d_in[16];
  const float* wf2 = (const float*)d_in[17];
  const float* bf2 = (const float*)d_in[18];
  float* out = (float*)d_out;

  char* base = (char*)d_ws;
  const size_t MB = 1024 * 1024;
  _Float16* norm1h = (_Float16*)(base);          // [0,2)
  _Float16* norm1l = (_Float16*)(base + 2*MB);   // [2,4)
  _Float16* qkv16  = (_Float16*)(base + 4*MB);   // [4,10): [4096][768]
  _Float16* vtb    = (_Float16*)(base + 10*MB);  // [10,12): [2][256][2048]
  _Float16* atth   = (_Float16*)(base + 12*MB);  // [12,14)
  _Float16* attl   = (_Float16*)(base + 14*MB);  // [14,16)
  float*    hid2   = (float*)(base + 16*MB);     // [16,20) f32
  // attn partials [20,36); ffa overlays the same region after combine+WO+LN2:
  float* Opart = (float*)(base + 20*MB);         // 16 MB: [8][8][2048][32] f32
  _Float16* ffah = (_Float16*)(base + 20*MB);    // [20,28): [4096][1024]
  _Float16* ffal = (_Float16*)(base + 28*MB);    // [28,36)
  float* Mpart = (float*)(base + 36*MB);         // 512 KB
  float* Spart = (float*)(base + 36*MB + 512*1024);
  _Float16* wtb = (_Float16*)(base + 37*MB);
  _Float16* WtQKVh = wtb; wtb += 768 * 256;
  _Float16* WtQKVl = wtb; wtb += 768 * 256;
  _Float16* WtOh   = wtb; wtb += 256 * 256;
  _Float16* WtOl   = wtb; wtb += 256 * 256;
  _Float16* WtF1h  = wtb; wtb += 1024 * 256;
  _Float16* WtF1l  = wtb; wtb += 1024 * 256;
  _Float16* WtF2h  = wtb; wtb += 256 * 1024;
  _Float16* WtF2l  = wtb; wtb += 256 * 1024;
  float* biasqkv = (float*)(base + 41*MB);

  prep_kernel<<<769, 256, 0, stream>>>(wq, wk, wv, wo, wf1, wf2, bq, bk, bv,
      WtQKVh, WtQKVl, WtOh, WtOl, WtF1h, WtF1l, WtF2h, WtF2l, biasqkv);

  ln_kernel<<<NTOK / 4, 256, 0, stream>>>(hidden, g1, b1, norm1h, norm1l);

  // fused QKV -> fp16 qkv (Q,K) + transposed pair-interleaved fp16 V
  gemm_mfma_kernel<256, 4, 0, 0, 2><<<dim3(12, 64), 256, 0, stream>>>(
      norm1h, norm1l, WtQKVh, WtQKVl, biasqkv, nullptr,
      nullptr, qkv16, nullptr, vtb, QKVLD);

  attn_mfma_kernel<<<dim3(NN / 64, NH, BB * NSPLIT), 256, 0, stream>>>(
      qkv16, vtb, adjacency, Opart, Mpart, Spart);
  attn_combine_kernel<<<(BB * NH * NN * 8) / 256, 256, 0, stream>>>(
      Opart, Mpart, Spart, atth, attl);

  gemm_mfma_kernel<256, 2, 0, 1, 0><<<dim3(8, 64), 256, 0, stream>>>(
      atth, attl, WtOh, WtOl, bo, hidden,
      hid2, nullptr, nullptr, nullptr, 256);

  ln_kernel<<<NTOK / 4, 256, 0, stream>>>(hid2, g2, b2, norm1h, norm1l);

  gemm_mfma_kernel<256, 4, 1, 0, 1><<<dim3(16, 64), 256, 0, stream>>>(
      norm1h, norm1l, WtF1h, WtF1l, bf1, nullptr,
      nullptr, ffah, ffal, nullptr, 1024);

  gemm_mfma_kernel<1024, 2, 0, 1, 0><<<dim3(8, 64), 256, 0, stream>>>(
      ffah, ffal, WtF2h, WtF2l, bf2, hid2,
      out, nullptr, nullptr, nullptr, 256);
}

// Round 10
// 133.371 us; speedup vs baseline: 3.5895x; 1.4197x over previous
//
#include <hip/hip_runtime.h>
#include <math.h>

#define BB 2
#define NN 2048
#define HD 256
#define NH 8
#define DH 32
#define NTOK (BB*NN)   // 4096
#define QKVLD 768      // fused qkv row stride (fp16)
#define NSPLIT 4       // split-KV ways

typedef _Float16 h8 __attribute__((ext_vector_type(8)));
typedef _Float16 h4 __attribute__((ext_vector_type(4)));
typedef float fx4 __attribute__((ext_vector_type(4)));

#define LOG2E 1.4426950408889634f
#define SQ_LOG2 0.25503486f   // log2(e)/sqrt(32), folded into wq/bq

// ---------------- LayerNorm: f32 in -> fp16 out ----------------
__global__ __launch_bounds__(256) void ln_kernel(const float* __restrict__ x,
    const float* __restrict__ g, const float* __restrict__ bta,
    _Float16* __restrict__ yh)
{
  int row  = blockIdx.x * 4 + (threadIdx.x >> 6);
  int lane = threadIdx.x & 63;
  const float* xr = x + (size_t)row * HD + lane * 4;
  float4 v = *(const float4*)xr;
  float s = v.x + v.y + v.z + v.w;
  #pragma unroll
  for (int off = 32; off > 0; off >>= 1) s += __shfl_xor(s, off);
  float mu = s * (1.0f / HD);
  float dx0 = v.x - mu, dx1 = v.y - mu, dx2 = v.z - mu, dx3 = v.w - mu;
  float ss = dx0*dx0 + dx1*dx1 + dx2*dx2 + dx3*dx3;
  #pragma unroll
  for (int off = 32; off > 0; off >>= 1) ss += __shfl_xor(ss, off);
  float rinv = rsqrtf(ss * (1.0f / HD) + 1e-5f);
  float4 gv = *(const float4*)(g   + lane * 4);
  float4 bv = *(const float4*)(bta + lane * 4);
  float o[4];
  o[0] = dx0 * rinv * gv.x + bv.x;
  o[1] = dx1 * rinv * gv.y + bv.y;
  o[2] = dx2 * rinv * gv.z + bv.z;
  o[3] = dx3 * rinv * gv.w + bv.w;
  h4 hh;
  #pragma unroll
  for (int j = 0; j < 4; j++) hh[j] = (_Float16)o[j];
  *(h4*)(yh + (size_t)row * HD + lane * 4) = hh;
}

// ---------------- fused prep: weight transposes (fp16, hi only) + bias concat -------
__device__ __forceinline__ void do_transpose(const float* __restrict__ W,
    _Float16* __restrict__ Wh, int Nw, int rowoff, int ldout, float scale,
    int bx, int by, float (*tile)[33])
{
  int k0 = by * 32, n0 = bx * 32;
  int c = threadIdx.x & 31, r = threadIdx.x >> 5;   // r 0..7
  #pragma unroll
  for (int i = 0; i < 4; i++)
    tile[r + i * 8][c] = W[(size_t)(k0 + r + i * 8) * Nw + n0 + c];
  __syncthreads();
  #pragma unroll
  for (int i = 0; i < 4; i++) {
    int n = r + i * 8;
    Wh[(size_t)(rowoff + n0 + n) * ldout + k0 + c] = (_Float16)(tile[c][n] * scale);
  }
}

__global__ __launch_bounds__(256) void prep_kernel(
    const float* wq, const float* wk, const float* wv, const float* wo,
    const float* wf1, const float* wf2,
    const float* bq, const float* bk, const float* bv,
    _Float16* WtQKVh, _Float16* WtOh, _Float16* WtF1h, _Float16* WtF2h,
    float* biasqkv)
{
  __shared__ float tile[32][33];
  int bid = blockIdx.x;
  if (bid < 64)        do_transpose(wq,  WtQKVh,  256,   0,  256, SQ_LOG2, bid & 7, bid >> 3, tile);
  else if (bid < 128)  do_transpose(wk,  WtQKVh,  256, 256,  256, 1.0f, (bid-64) & 7, (bid-64) >> 3, tile);
  else if (bid < 192)  do_transpose(wv,  WtQKVh,  256, 512,  256, 1.0f, (bid-128) & 7, (bid-128) >> 3, tile);
  else if (bid < 256)  do_transpose(wo,  WtOh,    256,   0,  256, 1.0f, (bid-192) & 7, (bid-192) >> 3, tile);
  else if (bid < 512)  do_transpose(wf1, WtF1h,  1024,   0,  256, 1.0f, (bid-256) & 31, (bid-256) >> 5, tile);
  else if (bid < 768)  do_transpose(wf2, WtF2h,   256,   0, 1024, 1.0f, (bid-512) & 7, (bid-512) >> 3, tile);
  else {
    #pragma unroll
    for (int j = 0; j < 3; j++) {
      int t = j * 256 + threadIdx.x;
      biasqkv[t] = (t < 256) ? bq[t] * SQ_LOG2 : (t < 512) ? bk[t - 256] : bv[t - 512];
    }
  }
}

// ---------------- pure-fp16 MFMA GEMM, direct-fragment, XCD-bijective swizzle -------
// 1D grid, n-major logical order: wg = (lin&7)*(nwg/8) + lin>>3 -> blocks sharing
// A-rows are XCD-contiguous (A read once per XCD; W stays L2-resident).
// OM: 0 = f32 C (+resid); 1 = fp16 out; 2 = qkv (fp16 + V transposed/pair-interleaved)
template<int KK, int NT, int NX, int ACT, int RES, int OM>
__global__ __launch_bounds__(256) void gemm16_kernel(
    const _Float16* __restrict__ Ah, const _Float16* __restrict__ Wh,
    const float* __restrict__ bias, const float* __restrict__ resid,
    float* __restrict__ Cf, _Float16* __restrict__ Ch,
    _Float16* __restrict__ vtb, int N)
{
  const int lin = blockIdx.x;
  const int qch = gridDim.x >> 3;
  const int wg = (lin & 7) * qch + (lin >> 3);   // bijective (nwg % 8 == 0)
  const int bx = wg % NX, by = wg / NX;
  const int n0 = bx * (NT * 16);
  const int m0 = by * 64;
  const int t = threadIdx.x, w = t >> 6, l = t & 63;
  const int ml = l & 15, g = l >> 4;
  const int mrow = m0 + w * 16 + ml;

  const _Float16* aph = Ah + (size_t)mrow * KK + g * 8;
  const _Float16* whp[NT];
  #pragma unroll
  for (int nt = 0; nt < NT; nt++)
    whp[nt] = Wh + (size_t)(n0 + nt * 16 + ml) * KK + g * 8;

  fx4 acc[NT];
  #pragma unroll
  for (int nt = 0; nt < NT; nt++) acc[nt] = (fx4){0.f, 0.f, 0.f, 0.f};

  #pragma unroll 4
  for (int k0 = 0; k0 < KK; k0 += 32) {
    h8 ah = *(const h8*)(aph + k0);
    #pragma unroll
    for (int nt = 0; nt < NT; nt++) {
      h8 wh = *(const h8*)(whp[nt] + k0);
      acc[nt] = __builtin_amdgcn_mfma_f32_16x16x32_f16(ah, wh, acc[nt], 0, 0, 0);
    }
  }

  #pragma unroll
  for (int nt = 0; nt < NT; nt++) {
    int n = n0 + nt * 16 + ml;
    float bv = bias[n];
    #pragma unroll
    for (int i = 0; i < 4; i++) {
      int m = m0 + w * 16 + 4 * g + i;
      float vv = acc[nt][i] + bv;
      if (ACT == 1) vv = 0.5f * vv * (1.0f + erff(vv * 0.70710678118654752f));
      if (RES)      vv += resid[(size_t)m * N + n];
      if (OM == 0) {
        Cf[(size_t)m * N + n] = vv;
      } else if (OM == 1) {
        Ch[(size_t)m * N + n] = (_Float16)vv;
      } else {   // OM == 2: qkv; V transposed with pair-interleaved kv index
        if (n < 512) Ch[(size_t)m * QKVLD + n] = (_Float16)vv;
        else {
          int dim = n - 512, kv = m & (NN - 1), bb = m >> 11;
          int kvp = (kv & ~31) | ((kv & 15) << 1) | ((kv >> 4) & 1);
          vtb[((size_t)(bb * HD + dim)) * NN + kvp] = (_Float16)vv;
        }
      }
    }
  }
}

// ---------------- MFMA flash attention: fp16, 4-way split-KV, log2 softmax ----------
__global__ __launch_bounds__(256) void attn_mfma_kernel(
    const _Float16* __restrict__ qkv16, const _Float16* __restrict__ vtb,
    const float* __restrict__ adj,
    float* __restrict__ Opart, float* __restrict__ Mpart, float* __restrict__ Spart)
{
  __shared__ _Float16 Ksh[64][40];   // [kv][dim]
  __shared__ _Float16 Vp[32][72];    // [dim][kv' within tile]

  const int z = blockIdx.z;                  // b*NSPLIT + quarter
  const int b = z >> 2, quarter = z & 3;
  const int h = blockIdx.y;
  const int q0 = blockIdx.x * 64;
  const int t = threadIdx.x;
  const int w = t >> 6, l = t & 63;
  const int m = l & 15, g = l >> 4;
  const int kvbase = quarter * (NN / NSPLIT);   // 512 kv per block

  const int qrow = q0 + w * 16 + m;
  h8 qh = *(const h8*)(qkv16 + ((size_t)(b * NN + qrow)) * QKVLD + h * DH + g * 8);

  fx4 ot0 = {0.f, 0.f, 0.f, 0.f};
  fx4 ot1 = {0.f, 0.f, 0.f, 0.f};
  float M = -3.0e38f, S = 0.0f;

  const float* adjrow = adj + ((size_t)(b * NN + qrow)) * NN + kvbase;

  const int krow = t >> 2, kd0 = (t & 3) * 8;   // K staging
  const int vdim = t >> 3, vkc = (t & 7) * 8;   // V' staging
  const _Float16* kbase = qkv16 + ((size_t)(b * NN + kvbase + krow)) * QKVLD + 256 + h * DH + kd0;
  const _Float16* vbase = vtb + ((size_t)(b * HD + h * DH + vdim)) * NN + kvbase + vkc;
  h8 kreg = *(const h8*)kbase;
  h8 vreg = *(const h8*)vbase;
  float4 adjreg[4];
  #pragma unroll
  for (int p = 0; p < 4; p++) adjreg[p] = *(const float4*)(adjrow + p * 16 + g * 4);

  for (int kt = 0; kt < NN / NSPLIT; kt += 64) {
    __syncthreads();
    *(h8*)&Ksh[krow][kd0] = kreg;
    *(h8*)&Vp[vdim][vkc]  = vreg;
    __syncthreads();

    float4 a4[4];
    #pragma unroll
    for (int p = 0; p < 4; p++) a4[p] = adjreg[p];
    if (kt + 64 < NN / NSPLIT) {
      kreg = *(const h8*)(kbase + (size_t)(kt + 64) * QKVLD);
      vreg = *(const h8*)(vbase + kt + 64);
      #pragma unroll
      for (int p = 0; p < 4; p++) adjreg[p] = *(const float4*)(adjrow + kt + 64 + p * 16 + g * 4);
    }

    // ---- QK^T for the 64-kv tile (log2-domain logits) ----
    h8 kh0 = *(const h8*)&Ksh[     m][g * 8];
    h8 kh1 = *(const h8*)&Ksh[16 + m][g * 8];
    h8 kh2 = *(const h8*)&Ksh[32 + m][g * 8];
    h8 kh3 = *(const h8*)&Ksh[48 + m][g * 8];
    fx4 z4 = {0.f, 0.f, 0.f, 0.f};
    fx4 st[4];
    st[0] = __builtin_amdgcn_mfma_f32_16x16x32_f16(kh0, qh, z4, 0, 0, 0);
    st[1] = __builtin_amdgcn_mfma_f32_16x16x32_f16(kh1, qh, z4, 0, 0, 0);
    st[2] = __builtin_amdgcn_mfma_f32_16x16x32_f16(kh2, qh, z4, 0, 0, 0);
    st[3] = __builtin_amdgcn_mfma_f32_16x16x32_f16(kh3, qh, z4, 0, 0, 0);

    float lv[16];
    float tmax = -3.0e38f;
    #pragma unroll
    for (int p = 0; p < 4; p++) {
      const float* ap = (const float*)&a4[p];
      #pragma unroll
      for (int i = 0; i < 4; i++) {
        float lvv = st[p][i] + (2.0f * LOG2E) * ap[i] - LOG2E;
        lv[p * 4 + i] = lvv;
        tmax = fmaxf(tmax, lvv);
      }
    }
    tmax = fmaxf(tmax, __shfl_xor(tmax, 16));
    tmax = fmaxf(tmax, __shfl_xor(tmax, 32));
    if (!__all(tmax <= M + 8.0f)) {
      float mnew = fmaxf(M, tmax);
      float resc = __builtin_amdgcn_exp2f(M - mnew);
      S *= resc; ot0 *= resc; ot1 *= resc;
      M = mnew;
    }
    float pv[16];
    #pragma unroll
    for (int p = 0; p < 4; p++) {
      const float* ap = (const float*)&a4[p];
      #pragma unroll
      for (int i = 0; i < 4; i++) {
        float e = __builtin_amdgcn_exp2f(lv[p * 4 + i] - M);
        float pp = (0.25f + 0.75f * ap[i]) * e;
        pv[p * 4 + i] = pp;
        S += pp;
      }
    }
    // pack P in pair-interleaved k-slot order
    h8 ph0, ph1;
    #pragma unroll
    for (int q2 = 0; q2 < 4; q2++) {
      ph0[2*q2]     = (_Float16)pv[q2];
      ph0[2*q2 + 1] = (_Float16)pv[4 + q2];
      ph1[2*q2]     = (_Float16)pv[8 + q2];
      ph1[2*q2 + 1] = (_Float16)pv[12 + q2];
    }

    h8 v00 = *(const h8*)&Vp[m][g * 8];
    h8 v01 = *(const h8*)&Vp[m][32 + g * 8];
    h8 v10 = *(const h8*)&Vp[16 + m][g * 8];
    h8 v11 = *(const h8*)&Vp[16 + m][32 + g * 8];
    ot0 = __builtin_amdgcn_mfma_f32_16x16x32_f16(v00, ph0, ot0, 0, 0, 0);
    ot0 = __builtin_amdgcn_mfma_f32_16x16x32_f16(v01, ph1, ot0, 0, 0, 0);
    ot1 = __builtin_amdgcn_mfma_f32_16x16x32_f16(v10, ph0, ot1, 0, 0, 0);
    ot1 = __builtin_amdgcn_mfma_f32_16x16x32_f16(v11, ph1, ot1, 0, 0, 0);
  }

  S += __shfl_xor(S, 16);
  S += __shfl_xor(S, 32);

  size_t prow = ((size_t)(z * NH + h)) * NN + qrow;
  float* po = Opart + prow * 32;
  *(float4*)(po + 4 * g)      = make_float4(ot0[0], ot0[1], ot0[2], ot0[3]);
  *(float4*)(po + 16 + 4 * g) = make_float4(ot1[0], ot1[1], ot1[2], ot1[3]);
  if (g == 0) { Mpart[prow] = M; Spart[prow] = S; }
}

// ---------------- combine the NSPLIT KV quarters -> fp16 att ----------------
__global__ __launch_bounds__(256) void attn_combine_kernel(
    const float* __restrict__ Opart, const float* __restrict__ Mpart,
    const float* __restrict__ Spart, _Float16* __restrict__ atth)
{
  int idx = blockIdx.x * 256 + threadIdx.x;   // BB*NH*NN*8 total
  int dg  = idx & 7;
  int rowid = idx >> 3;
  int qrow = rowid & (NN - 1);
  int bh = rowid >> 11;
  int b = bh >> 3, h = bh & 7;
  size_t p[NSPLIT];
  float mz[NSPLIT], sz[NSPLIT];
  float mm = -3.0e38f;
  #pragma unroll
  for (int zq = 0; zq < NSPLIT; zq++) {
    p[zq] = ((size_t)((b * NSPLIT + zq) * NH + h)) * NN + qrow;
    mz[zq] = Mpart[p[zq]];
    sz[zq] = Spart[p[zq]];
    mm = fmaxf(mm, mz[zq]);
  }
  float den = 0.f;
  float ez[NSPLIT];
  #pragma unroll
  for (int zq = 0; zq < NSPLIT; zq++) {
    ez[zq] = __builtin_amdgcn_exp2f(mz[zq] - mm);
    den += sz[zq] * ez[zq];
  }
  float is = 1.0f / den;
  float ov[4] = {0.f, 0.f, 0.f, 0.f};
  #pragma unroll
  for (int zq = 0; zq < NSPLIT; zq++) {
    float4 o = *(const float4*)(Opart + p[zq] * 32 + dg * 4);
    ov[0] += o.x * ez[zq]; ov[1] += o.y * ez[zq];
    ov[2] += o.z * ez[zq]; ov[3] += o.w * ez[zq];
  }
  h4 hh;
  #pragma unroll
  for (int j = 0; j < 4; j++) hh[j] = (_Float16)(ov[j] * is);
  *(h4*)(atth + ((size_t)(b * NN + qrow)) * HD + h * DH + dg * 4) = hh;
}

extern "C" void kernel_launch(void* const* d_in, const int* in_sizes, int n_in,
                              void* d_out, int out_size, void* d_ws, size_t ws_size,
                              hipStream_t stream)
{
  const float* hidden    = (const float*)d_in[0];
  const float* adjacency = (const float*)d_in[1];
  const float* wq  = (const float*)d_in[3];
  const float* bq  = (const float*)d_in[4];
  const float* wk  = (const float*)d_in[5];
  const float* bk  = (const float*)d_in[6];
  const float* wv  = (const float*)d_in[7];
  const float* bv  = (const float*)d_in[8];
  const float* wo  = (const float*)d_in[9];
  const float* bo  = (const float*)d_in[10];
  const float* g1  = (const float*)d_in[11];
  const float* b1  = (const float*)d_in[12];
  const float* g2  = (const float*)d_in[13];
  const float* b2  = (const float*)d_in[14];
  const float* wf1 = (const float*)d_in[15];
  const float* bf1 = (const float*)d_in[16];
  const float* wf2 = (const float*)d_in[17];
  const float* bf2 = (const float*)d_in[18];
  float* out = (float*)d_out;

  char* base = (char*)d_ws;
  const size_t MB = 1024 * 1024;
  _Float16* norm1h = (_Float16*)(base);          // [0,2)
  _Float16* qkv16  = (_Float16*)(base + 4*MB);   // [4,10): [4096][768]
  _Float16* vtb    = (_Float16*)(base + 10*MB);  // [10,12): [2][256][2048]
  _Float16* atth   = (_Float16*)(base + 12*MB);  // [12,14)
  float*    hid2   = (float*)(base + 16*MB);     // [16,20) f32
  // attn partials [20,36); ffah overlays after combine (Opart dead by FF1 time):
  float* Opart = (float*)(base + 20*MB);         // 16 MB: [8][8][2048][32] f32
  _Float16* ffah = (_Float16*)(base + 20*MB);    // [20,28): [4096][1024]
  float* Mpart = (float*)(base + 36*MB);         // 512 KB
  float* Spart = (float*)(base + 36*MB + 512*1024);
  _Float16* wtb = (_Float16*)(base + 37*MB);
  _Float16* WtQKVh = wtb; wtb += 768 * 256;
  _Float16* WtOh   = wtb; wtb += 256 * 256;
  _Float16* WtF1h  = wtb; wtb += 1024 * 256;
  _Float16* WtF2h  = wtb; wtb += 256 * 1024;
  float* biasqkv = (float*)(base + 40*MB);

  prep_kernel<<<769, 256, 0, stream>>>(wq, wk, wv, wo, wf1, wf2, bq, bk, bv,
      WtQKVh, WtOh, WtF1h, WtF2h, biasqkv);

  ln_kernel<<<NTOK / 4, 256, 0, stream>>>(hidden, g1, b1, norm1h);

  // fused QKV -> fp16 qkv (Q,K) + transposed pair-interleaved fp16 V
  gemm16_kernel<256, 4, 12, 0, 0, 2><<<768, 256, 0, stream>>>(
      norm1h, WtQKVh, biasqkv, nullptr, nullptr, qkv16, vtb, QKVLD);

  attn_mfma_kernel<<<dim3(NN / 64, NH, BB * NSPLIT), 256, 0, stream>>>(
      qkv16, vtb, adjacency, Opart, Mpart, Spart);
  attn_combine_kernel<<<(BB * NH * NN * 8) / 256, 256, 0, stream>>>(
      Opart, Mpart, Spart, atth);

  gemm16_kernel<256, 2, 8, 0, 1, 0><<<512, 256, 0, stream>>>(
      atth, WtOh, bo, hidden, hid2, nullptr, nullptr, 256);

  ln_kernel<<<NTOK / 4, 256, 0, stream>>>(hid2, g2, b2, norm1h);

  gemm16_kernel<256, 4, 16, 1, 0, 1><<<1024, 256, 0, stream>>>(
      norm1h, WtF1h, bf1, nullptr, nullptr, ffah, nullptr, 1024);

  gemm16_kernel<1024, 2, 8, 0, 1, 0><<<512, 256, 0, stream>>>(
      ffah, WtF2h, bf2, hid2, out, nullptr, nullptr, 256);
}

// Round 11
// 131.995 us; speedup vs baseline: 3.6270x; 1.0104x over previous
//
#include <hip/hip_runtime.h>
#include <math.h>

#define BB 2
#define NN 2048
#define HD 256
#define NH 8
#define DH 32
#define NTOK (BB*NN)   // 4096
#define QKVLD 768      // fused qkv row stride (fp16)
#define NSPLIT 4       // split-KV ways

typedef _Float16 h8 __attribute__((ext_vector_type(8)));
typedef _Float16 h4 __attribute__((ext_vector_type(4)));
typedef float fx4 __attribute__((ext_vector_type(4)));

#define LOG2E 1.4426950408889634f
#define SQ_LOG2 0.25503486f   // log2(e)/sqrt(32), folded into wq/bq

// ---------------- LayerNorm: f32 in -> fp16 out ----------------
__global__ __launch_bounds__(256) void ln_kernel(const float* __restrict__ x,
    const float* __restrict__ g, const float* __restrict__ bta,
    _Float16* __restrict__ yh)
{
  int row  = blockIdx.x * 4 + (threadIdx.x >> 6);
  int lane = threadIdx.x & 63;
  const float* xr = x + (size_t)row * HD + lane * 4;
  float4 v = *(const float4*)xr;
  float s = v.x + v.y + v.z + v.w;
  #pragma unroll
  for (int off = 32; off > 0; off >>= 1) s += __shfl_xor(s, off);
  float mu = s * (1.0f / HD);
  float dx0 = v.x - mu, dx1 = v.y - mu, dx2 = v.z - mu, dx3 = v.w - mu;
  float ss = dx0*dx0 + dx1*dx1 + dx2*dx2 + dx3*dx3;
  #pragma unroll
  for (int off = 32; off > 0; off >>= 1) ss += __shfl_xor(ss, off);
  float rinv = rsqrtf(ss * (1.0f / HD) + 1e-5f);
  float4 gv = *(const float4*)(g   + lane * 4);
  float4 bv = *(const float4*)(bta + lane * 4);
  float o[4];
  o[0] = dx0 * rinv * gv.x + bv.x;
  o[1] = dx1 * rinv * gv.y + bv.y;
  o[2] = dx2 * rinv * gv.z + bv.z;
  o[3] = dx3 * rinv * gv.w + bv.w;
  h4 hh;
  #pragma unroll
  for (int j = 0; j < 4; j++) hh[j] = (_Float16)o[j];
  *(h4*)(yh + (size_t)row * HD + lane * 4) = hh;
}

// ---------------- fused prep: weight transposes (fp16) + bias concat -------
__device__ __forceinline__ void do_transpose(const float* __restrict__ W,
    _Float16* __restrict__ Wh, int Nw, int rowoff, int ldout, float scale,
    int bx, int by, float (*tile)[33])
{
  int k0 = by * 32, n0 = bx * 32;
  int c = threadIdx.x & 31, r = threadIdx.x >> 5;   // r 0..7
  #pragma unroll
  for (int i = 0; i < 4; i++)
    tile[r + i * 8][c] = W[(size_t)(k0 + r + i * 8) * Nw + n0 + c];
  __syncthreads();
  #pragma unroll
  for (int i = 0; i < 4; i++) {
    int n = r + i * 8;
    Wh[(size_t)(rowoff + n0 + n) * ldout + k0 + c] = (_Float16)(tile[c][n] * scale);
  }
}

__global__ __launch_bounds__(256) void prep_kernel(
    const float* wq, const float* wk, const float* wv, const float* wo,
    const float* wf1, const float* wf2,
    const float* bq, const float* bk, const float* bv,
    _Float16* WtQKVh, _Float16* WtOh, _Float16* WtF1h, _Float16* WtF2h,
    float* biasqkv)
{
  __shared__ float tile[32][33];
  int bid = blockIdx.x;
  if (bid < 64)        do_transpose(wq,  WtQKVh,  256,   0,  256, SQ_LOG2, bid & 7, bid >> 3, tile);
  else if (bid < 128)  do_transpose(wk,  WtQKVh,  256, 256,  256, 1.0f, (bid-64) & 7, (bid-64) >> 3, tile);
  else if (bid < 192)  do_transpose(wv,  WtQKVh,  256, 512,  256, 1.0f, (bid-128) & 7, (bid-128) >> 3, tile);
  else if (bid < 256)  do_transpose(wo,  WtOh,    256,   0,  256, 1.0f, (bid-192) & 7, (bid-192) >> 3, tile);
  else if (bid < 512)  do_transpose(wf1, WtF1h,  1024,   0,  256, 1.0f, (bid-256) & 31, (bid-256) >> 5, tile);
  else if (bid < 768)  do_transpose(wf2, WtF2h,   256,   0, 1024, 1.0f, (bid-512) & 7, (bid-512) >> 3, tile);
  else {
    #pragma unroll
    for (int j = 0; j < 3; j++) {
      int t = j * 256 + threadIdx.x;
      biasqkv[t] = (t < 256) ? bq[t] * SQ_LOG2 : (t < 512) ? bk[t - 256] : bv[t - 512];
    }
  }
}

// ---------------- pure-fp16 MFMA GEMM, direct-fragment, XCD-bijective swizzle -------
template<int KK, int NT, int NX, int ACT, int RES, int OM>
__global__ __launch_bounds__(256) void gemm16_kernel(
    const _Float16* __restrict__ Ah, const _Float16* __restrict__ Wh,
    const float* __restrict__ bias, const float* __restrict__ resid,
    float* __restrict__ Cf, _Float16* __restrict__ Ch,
    _Float16* __restrict__ vtb, int N)
{
  const int lin = blockIdx.x;
  const int qch = gridDim.x >> 3;
  const int wg = (lin & 7) * qch + (lin >> 3);   // bijective (nwg % 8 == 0)
  const int bx = wg % NX, by = wg / NX;
  const int n0 = bx * (NT * 16);
  const int m0 = by * 64;
  const int t = threadIdx.x, w = t >> 6, l = t & 63;
  const int ml = l & 15, g = l >> 4;
  const int mrow = m0 + w * 16 + ml;

  const _Float16* aph = Ah + (size_t)mrow * KK + g * 8;
  const _Float16* whp[NT];
  #pragma unroll
  for (int nt = 0; nt < NT; nt++)
    whp[nt] = Wh + (size_t)(n0 + nt * 16 + ml) * KK + g * 8;

  fx4 acc[NT];
  #pragma unroll
  for (int nt = 0; nt < NT; nt++) acc[nt] = (fx4){0.f, 0.f, 0.f, 0.f};

  #pragma unroll 4
  for (int k0 = 0; k0 < KK; k0 += 32) {
    h8 ah = *(const h8*)(aph + k0);
    #pragma unroll
    for (int nt = 0; nt < NT; nt++) {
      h8 wh = *(const h8*)(whp[nt] + k0);
      acc[nt] = __builtin_amdgcn_mfma_f32_16x16x32_f16(ah, wh, acc[nt], 0, 0, 0);
    }
  }

  #pragma unroll
  for (int nt = 0; nt < NT; nt++) {
    int n = n0 + nt * 16 + ml;
    float bv = bias[n];
    #pragma unroll
    for (int i = 0; i < 4; i++) {
      int m = m0 + w * 16 + 4 * g + i;
      float vv = acc[nt][i] + bv;
      if (ACT == 1) vv = 0.5f * vv * (1.0f + erff(vv * 0.70710678118654752f));
      if (RES)      vv += resid[(size_t)m * N + n];
      if (OM == 0) {
        Cf[(size_t)m * N + n] = vv;
      } else if (OM == 1) {
        Ch[(size_t)m * N + n] = (_Float16)vv;
      } else {   // OM == 2: qkv; V transposed with pair-interleaved kv index
        if (n < 512) Ch[(size_t)m * QKVLD + n] = (_Float16)vv;
        else {
          int dim = n - 512, kv = m & (NN - 1), bb = m >> 11;
          int kvp = (kv & ~31) | ((kv & 15) << 1) | ((kv >> 4) & 1);
          vtb[((size_t)(bb * HD + dim)) * NN + kvp] = (_Float16)vv;
        }
      }
    }
  }
}

// ---------------- MFMA flash attention: fp16, split-KV, DOUBLE-BUFFERED LDS ----------
// One barrier per 64-kv tile; compute tile t from buf[t&1] while regs for t+1 are
// written to buf[t&1^1] after compute. Lane-local defer-max check (ballot is over
// all lanes, so per-lane tmax suffices for the rescale condition); max-reduce only
// inside the rare rescale branch. Partials stored NORMALIZED (O/S) in fp16.
__global__ __launch_bounds__(256) void attn_mfma_kernel(
    const _Float16* __restrict__ qkv16, const _Float16* __restrict__ vtb,
    const float* __restrict__ adj,
    _Float16* __restrict__ Opart, float* __restrict__ Mpart, float* __restrict__ Spart)
{
  __shared__ _Float16 Ksh[2][64][40];   // [buf][kv][dim]   2*2560*2B
  __shared__ _Float16 Vp[2][32][72];    // [buf][dim][kv']  2*2304*2B  -> 19456 B total

  const int z = blockIdx.z;                  // b*NSPLIT + quarter
  const int b = z >> 2, quarter = z & 3;
  const int h = blockIdx.y;
  const int q0 = blockIdx.x * 64;
  const int t = threadIdx.x;
  const int w = t >> 6, l = t & 63;
  const int m = l & 15, g = l >> 4;
  const int kvbase = quarter * (NN / NSPLIT);   // 512 kv per block
  const int NTILES = NN / NSPLIT / 64;          // 8

  const int qrow = q0 + w * 16 + m;
  h8 qh = *(const h8*)(qkv16 + ((size_t)(b * NN + qrow)) * QKVLD + h * DH + g * 8);

  fx4 ot0 = {0.f, 0.f, 0.f, 0.f};
  fx4 ot1 = {0.f, 0.f, 0.f, 0.f};
  float M = -3.0e38f, S = 0.0f;

  const float* adjrow = adj + ((size_t)(b * NN + qrow)) * NN + kvbase;

  const int krow = t >> 2, kd0 = (t & 3) * 8;   // K staging role
  const int vdim = t >> 3, vkc = (t & 7) * 8;   // V' staging role
  const _Float16* kbase = qkv16 + ((size_t)(b * NN + kvbase + krow)) * QKVLD + 256 + h * DH + kd0;
  const _Float16* vbase = vtb + ((size_t)(b * HD + h * DH + vdim)) * NN + kvbase + vkc;

  h8 kreg = *(const h8*)kbase;
  h8 vreg = *(const h8*)vbase;
  float4 adjreg[4];
  #pragma unroll
  for (int p = 0; p < 4; p++) adjreg[p] = *(const float4*)(adjrow + p * 16 + g * 4);

  // prologue: stage tile 0 into buf0, issue tile-1 loads, one barrier
  *(h8*)&Ksh[0][krow][kd0] = kreg;
  *(h8*)&Vp[0][vdim][vkc]  = vreg;
  kreg = *(const h8*)(kbase + (size_t)64 * QKVLD);
  vreg = *(const h8*)(vbase + 64);
  __syncthreads();

  for (int tt = 0; tt < NTILES; ++tt) {
    const int cur = tt & 1;
    float4 a4[4];
    #pragma unroll
    for (int p = 0; p < 4; p++) a4[p] = adjreg[p];
    if (tt + 1 < NTILES) {
      #pragma unroll
      for (int p = 0; p < 4; p++)
        adjreg[p] = *(const float4*)(adjrow + (tt + 1) * 64 + p * 16 + g * 4);
    }

    // ---- QK^T for the 64-kv tile (log2-domain logits) ----
    h8 kh0 = *(const h8*)&Ksh[cur][     m][g * 8];
    h8 kh1 = *(const h8*)&Ksh[cur][16 + m][g * 8];
    h8 kh2 = *(const h8*)&Ksh[cur][32 + m][g * 8];
    h8 kh3 = *(const h8*)&Ksh[cur][48 + m][g * 8];
    fx4 z4 = {0.f, 0.f, 0.f, 0.f};
    fx4 st[4];
    st[0] = __builtin_amdgcn_mfma_f32_16x16x32_f16(kh0, qh, z4, 0, 0, 0);
    st[1] = __builtin_amdgcn_mfma_f32_16x16x32_f16(kh1, qh, z4, 0, 0, 0);
    st[2] = __builtin_amdgcn_mfma_f32_16x16x32_f16(kh2, qh, z4, 0, 0, 0);
    st[3] = __builtin_amdgcn_mfma_f32_16x16x32_f16(kh3, qh, z4, 0, 0, 0);

    float lv[16];
    #pragma unroll
    for (int p = 0; p < 4; p++) {
      const float* ap = (const float*)&a4[p];
      #pragma unroll
      for (int i = 0; i < 4; i++)
        lv[p * 4 + i] = st[p][i] + (2.0f * LOG2E) * ap[i] - LOG2E;
    }
    // lane-local max via 4-deep tree
    float x8[8];
    #pragma unroll
    for (int i = 0; i < 8; i++) x8[i] = fmaxf(lv[i], lv[i + 8]);
    float x4[4];
    #pragma unroll
    for (int i = 0; i < 4; i++) x4[i] = fmaxf(x8[i], x8[i + 4]);
    float lmax = fmaxf(fmaxf(x4[0], x4[1]), fmaxf(x4[2], x4[3]));
    // defer-max: __all over all 64 lanes == all rows' tile-max within M+8
    if (!__all(lmax <= M + 8.0f)) {
      float rmax = fmaxf(lmax, __shfl_xor(lmax, 16));
      rmax = fmaxf(rmax, __shfl_xor(rmax, 32));
      float mnew = fmaxf(M, rmax);
      float resc = __builtin_amdgcn_exp2f(M - mnew);
      S *= resc; ot0 *= resc; ot1 *= resc;
      M = mnew;
    }
    #pragma unroll
    for (int p = 0; p < 4; p++) {
      const float* ap = (const float*)&a4[p];
      #pragma unroll
      for (int i = 0; i < 4; i++) {
        float e = __builtin_amdgcn_exp2f(lv[p * 4 + i] - M);
        float pp = (0.25f + 0.75f * ap[i]) * e;
        lv[p * 4 + i] = pp;           // reuse storage
        S += pp;
      }
    }
    // pack P in pair-interleaved k-slot order
    h8 ph0, ph1;
    #pragma unroll
    for (int q2 = 0; q2 < 4; q2++) {
      ph0[2*q2]     = (_Float16)lv[q2];
      ph0[2*q2 + 1] = (_Float16)lv[4 + q2];
      ph1[2*q2]     = (_Float16)lv[8 + q2];
      ph1[2*q2 + 1] = (_Float16)lv[12 + q2];
    }

    // ---- PV from buf[cur] ----
    h8 v00 = *(const h8*)&Vp[cur][m][g * 8];
    h8 v01 = *(const h8*)&Vp[cur][m][32 + g * 8];
    h8 v10 = *(const h8*)&Vp[cur][16 + m][g * 8];
    h8 v11 = *(const h8*)&Vp[cur][16 + m][32 + g * 8];
    ot0 = __builtin_amdgcn_mfma_f32_16x16x32_f16(v00, ph0, ot0, 0, 0, 0);
    ot0 = __builtin_amdgcn_mfma_f32_16x16x32_f16(v01, ph1, ot0, 0, 0, 0);
    ot1 = __builtin_amdgcn_mfma_f32_16x16x32_f16(v10, ph0, ot1, 0, 0, 0);
    ot1 = __builtin_amdgcn_mfma_f32_16x16x32_f16(v11, ph1, ot1, 0, 0, 0);

    // ---- stage tile tt+1 into the other buffer; issue tt+2 loads ----
    if (tt + 1 < NTILES) {
      *(h8*)&Ksh[cur ^ 1][krow][kd0] = kreg;
      *(h8*)&Vp[cur ^ 1][vdim][vkc]  = vreg;
      if (tt + 2 < NTILES) {
        kreg = *(const h8*)(kbase + (size_t)((tt + 2) * 64) * QKVLD);
        vreg = *(const h8*)(vbase + (tt + 2) * 64);
      }
    }
    __syncthreads();
  }

  // denominator: per-lane partial -> reduce across lane^16, lane^32
  S += __shfl_xor(S, 16);
  S += __shfl_xor(S, 32);

  // store NORMALIZED partials in fp16 (|O/S| <= max|v|; S >= 0.25)
  float is = 1.0f / S;
  size_t prow = ((size_t)(z * NH + h)) * NN + qrow;
  _Float16* po = Opart + prow * 32;
  h4 o0h, o1h;
  #pragma unroll
  for (int j = 0; j < 4; j++) {
    o0h[j] = (_Float16)(ot0[j] * is);
    o1h[j] = (_Float16)(ot1[j] * is);
  }
  *(h4*)(po + 4 * g)      = o0h;
  *(h4*)(po + 16 + 4 * g) = o1h;
  if (g == 0) { Mpart[prow] = M; Spart[prow] = S; }
}

// ---------------- combine the NSPLIT KV quarters -> fp16 att ----------------
__global__ __launch_bounds__(256) void attn_combine_kernel(
    const _Float16* __restrict__ Opart, const float* __restrict__ Mpart,
    const float* __restrict__ Spart, _Float16* __restrict__ atth)
{
  int idx = blockIdx.x * 256 + threadIdx.x;   // BB*NH*NN*8 total
  int dg  = idx & 7;
  int rowid = idx >> 3;
  int qrow = rowid & (NN - 1);
  int bh = rowid >> 11;
  int b = bh >> 3, h = bh & 7;
  size_t p[NSPLIT];
  float mz[NSPLIT], sz[NSPLIT];
  float mm = -3.0e38f;
  #pragma unroll
  for (int zq = 0; zq < NSPLIT; zq++) {
    p[zq] = ((size_t)((b * NSPLIT + zq) * NH + h)) * NN + qrow;
    mz[zq] = Mpart[p[zq]];
    sz[zq] = Spart[p[zq]];
    mm = fmaxf(mm, mz[zq]);
  }
  float den = 0.f;
  float wz[NSPLIT];
  #pragma unroll
  for (int zq = 0; zq < NSPLIT; zq++) {
    wz[zq] = sz[zq] * __builtin_amdgcn_exp2f(mz[zq] - mm);
    den += wz[zq];
  }
  float is = 1.0f / den;
  float ov[4] = {0.f, 0.f, 0.f, 0.f};
  #pragma unroll
  for (int zq = 0; zq < NSPLIT; zq++) {
    h4 o = *(const h4*)(Opart + p[zq] * 32 + dg * 4);
    float wzz = wz[zq] * is;
    #pragma unroll
    for (int j = 0; j < 4; j++) ov[j] += wzz * (float)o[j];
  }
  h4 hh;
  #pragma unroll
  for (int j = 0; j < 4; j++) hh[j] = (_Float16)ov[j];
  *(h4*)(atth + ((size_t)(b * NN + qrow)) * HD + h * DH + dg * 4) = hh;
}

extern "C" void kernel_launch(void* const* d_in, const int* in_sizes, int n_in,
                              void* d_out, int out_size, void* d_ws, size_t ws_size,
                              hipStream_t stream)
{
  const float* hidden    = (const float*)d_in[0];
  const float* adjacency = (const float*)d_in[1];
  const float* wq  = (const float*)d_in[3];
  const float* bq  = (const float*)d_in[4];
  const float* wk  = (const float*)d_in[5];
  const float* bk  = (const float*)d_in[6];
  const float* wv  = (const float*)d_in[7];
  const float* bv  = (const float*)d_in[8];
  const float* wo  = (const float*)d_in[9];
  const float* bo  = (const float*)d_in[10];
  const float* g1  = (const float*)d_in[11];
  const float* b1  = (const float*)d_in[12];
  const float* g2  = (const float*)d_in[13];
  const float* b2  = (const float*)d_in[14];
  const float* wf1 = (const float*)d_in[15];
  const float* bf1 = (const float*)d_in[16];
  const float* wf2 = (const float*)d_in[17];
  const float* bf2 = (const float*)d_in[18];
  float* out = (float*)d_out;

  char* base = (char*)d_ws;
  const size_t MB = 1024 * 1024;
  _Float16* norm1h = (_Float16*)(base);          // [0,2)
  _Float16* qkv16  = (_Float16*)(base + 4*MB);   // [4,10): [4096][768]
  _Float16* vtb    = (_Float16*)(base + 10*MB);  // [10,12): [2][256][2048]
  _Float16* atth   = (_Float16*)(base + 12*MB);  // [12,14)
  float*    hid2   = (float*)(base + 16*MB);     // [16,20) f32
  // attn fp16 partials [20,28) = 8MB; ffah overlays after combine:
  _Float16* Opart = (_Float16*)(base + 20*MB);   // 8 MB: [8][8][2048][32] fp16
  _Float16* ffah  = (_Float16*)(base + 20*MB);   // [20,28): [4096][1024]
  float* Mpart = (float*)(base + 36*MB);         // 512 KB
  float* Spart = (float*)(base + 36*MB + 512*1024);
  _Float16* wtb = (_Float16*)(base + 37*MB);
  _Float16* WtQKVh = wtb; wtb += 768 * 256;
  _Float16* WtOh   = wtb; wtb += 256 * 256;
  _Float16* WtF1h  = wtb; wtb += 1024 * 256;
  _Float16* WtF2h  = wtb; wtb += 256 * 1024;
  float* biasqkv = (float*)(base + 40*MB);

  prep_kernel<<<769, 256, 0, stream>>>(wq, wk, wv, wo, wf1, wf2, bq, bk, bv,
      WtQKVh, WtOh, WtF1h, WtF2h, biasqkv);

  ln_kernel<<<NTOK / 4, 256, 0, stream>>>(hidden, g1, b1, norm1h);

  // fused QKV -> fp16 qkv (Q,K) + transposed pair-interleaved fp16 V
  gemm16_kernel<256, 4, 12, 0, 0, 2><<<768, 256, 0, stream>>>(
      norm1h, WtQKVh, biasqkv, nullptr, nullptr, qkv16, vtb, QKVLD);

  attn_mfma_kernel<<<dim3(NN / 64, NH, BB * NSPLIT), 256, 0, stream>>>(
      qkv16, vtb, adjacency, Opart, Mpart, Spart);
  attn_combine_kernel<<<(BB * NH * NN * 8) / 256, 256, 0, stream>>>(
      Opart, Mpart, Spart, atth);

  gemm16_kernel<256, 2, 8, 0, 1, 0><<<512, 256, 0, stream>>>(
      atth, WtOh, bo, hidden, hid2, nullptr, nullptr, 256);

  ln_kernel<<<NTOK / 4, 256, 0, stream>>>(hid2, g2, b2, norm1h);

  gemm16_kernel<256, 4, 16, 1, 0, 1><<<1024, 256, 0, stream>>>(
      norm1h, WtF1h, bf1, nullptr, nullptr, ffah, nullptr, 1024);

  gemm16_kernel<1024, 2, 8, 0, 1, 0><<<512, 256, 0, stream>>>(
      ffah, WtF2h, bf2, hid2, out, nullptr, nullptr, 256);
}